// Round 19
// baseline (446.133 us; speedup 1.0000x reference)
//
#include <hip/hip_runtime.h>
#include <math.h>

#define LL 256      // L
#define NS 128      // N sequences
#define DM 256      // d_msa
#define DH 32       // d_h
#define DP 128      // d_pair
#define HW 65536    // L*L

using u16 = unsigned short;
typedef __attribute__((ext_vector_type(8))) short s8v;   // 8 bf16 (A/B frag)
typedef __attribute__((ext_vector_type(4))) short s4v;   // 4 bf16
typedef __attribute__((ext_vector_type(4))) float f4v;   // C/D frag

#define MFMA(a, b, c) __builtin_amdgcn_mfma_f32_16x16x32_bf16((a), (b), (c), 0, 0, 0)

__device__ __forceinline__ u16 f2bf(float f) {
  unsigned u = __float_as_uint(f);
  u = (u + 0x7FFFu + ((u >> 16) & 1u)) >> 16;   // RNE
  return (u16)u;
}
__device__ __forceinline__ unsigned cvtpk2(float lo, float hi) {
  unsigned r;
  asm("v_cvt_pk_bf16_f32 %0, %1, %2" : "=v"(r) : "v"(lo), "v"(hi));
  return r;
}
__device__ __forceinline__ float bf2f(u16 h) { return __uint_as_float(((unsigned)h) << 16); }
__device__ __forceinline__ float elu1(float v) { return v > 0.f ? v : expm1f(v); }
__device__ __forceinline__ s8v zero8() {
  s8v v;
  #pragma unroll
  for (int j = 0; j < 8; ++j) v[j] = 0;
  return v;
}

// Fragment-tile layout: 1 KB tile = 16 rows x 32 k (bf16).
// unit(16B) = ((k>>3)&3)*16 + (row&15) ; elem = k&7.
// Wave fragment load = tile_base + lane*16 (fully coalesced).

// ---------------------------------------------------------------------------
// P: weight preps (fragment-tiled) + pairF + LayerNorm->msaF, one launch.
// ---------------------------------------------------------------------------
__device__ __forceinline__ void prep_convw(const float* __restrict__ w,
                                           u16* __restrict__ wP, int idx)
{
  int h = idx & 3, co = (idx >> 2) & 127, kk = (idx >> 9) & 3, tap = idx >> 11;
  s8v o;
  #pragma unroll
  for (int j = 0; j < 8; ++j) {
    int ci = kk * 32 + h * 8 + j;
    o[j] = (short)f2bf(w[((size_t)co * DP + ci) * 9 + tap]);
  }
  *(s8v*)(wP + (size_t)idx * 8) = o;
}

__global__ __launch_bounds__(256) void k_prep_ln(
    const float* __restrict__ Wl, const float* __restrict__ Wr,
    const float* __restrict__ Wo, const float* __restrict__ Wd,
    const float* __restrict__ conv1, const float* __restrict__ conv2,
    const float* __restrict__ pair,
    const float* __restrict__ msa, const float* __restrict__ ln_g,
    const float* __restrict__ ln_b,
    u16* __restrict__ WlrF, u16* __restrict__ WoF, u16* __restrict__ WdF,
    u16* __restrict__ wP1, u16* __restrict__ wP2, u16* __restrict__ pairF,
    u16* __restrict__ msaF)
{
  __shared__ alignas(16) u16 buf[16 * 264];
  int bx = blockIdx.x, t = threadIdx.x;
  if (bx < 64) {
    int o = bx * 256 + t;
    int tile = o >> 6, u = o & 63;
    int cblk = tile >> 5, j = tile & 31;
    int kslot = u >> 4, cl = u & 15;
    int c = cblk * 16 + cl;
    s8v v;
    #pragma unroll
    for (int e = 0; e < 8; ++e) {
      int i = kslot * 8 + e;
      v[e] = (short)f2bf(Wo[(size_t)(i * 32 + j) * DP + c]);
    }
    *(s8v*)(WoF + (size_t)o * 8) = v;
  } else if (bx < 80) {
    int o = (bx - 64) * 256 + t;
    int tile = o >> 6, u = o & 63;
    int cblk = tile >> 3, kch = tile & 7;
    int kslot = u >> 4, cl = u & 15;
    int c = cblk * 16 + cl;
    s8v v;
    #pragma unroll
    for (int e = 0; e < 8; ++e) {
      int k = kch * 32 + kslot * 8 + e;
      v[e] = (short)f2bf(Wd[(size_t)k * DP + c]);
    }
    *(s8v*)(WdF + (size_t)o * 8) = v;
  } else if (bx < 88) {
    int o = (bx - 80) * 256 + t;
    int tile = o >> 6, u = o & 63;
    int nblk = tile >> 3, kch = tile & 7;
    int kslot = u >> 4, cl = u & 15;
    int n = nblk * 16 + cl;
    s8v v;
    #pragma unroll
    for (int e = 0; e < 8; ++e) {
      int k = kch * 32 + kslot * 8 + e;
      float x = (n < 32) ? Wl[k * DH + n] : Wr[k * DH + (n - 32)];
      v[e] = (short)f2bf(x);
    }
    *(s8v*)(WlrF + (size_t)o * 8) = v;
  } else if (bx < 160) {
    prep_convw(conv1, wP1, (bx - 88) * 256 + t);
  } else if (bx < 232) {
    prep_convw(conv2, wP2, (bx - 160) * 256 + t);
  } else if (bx < 4328) {
    int pb = bx - 232;
    #pragma unroll
    for (int it = 0; it < 2; ++it) {
      int idx = it * 256 + t;
      int pix = idx >> 5, f4i = idx & 31;
      float4 v = ((const float4*)pair)[(size_t)(pb * 16 + pix) * 32 + f4i];
      s4v o;
      o[0] = (short)f2bf(v.x); o[1] = (short)f2bf(v.y);
      o[2] = (short)f2bf(v.z); o[3] = (short)f2bf(v.w);
      *(s4v*)(buf + pix * 136 + f4i * 4) = o;
    }
    __syncthreads();
    int kch = t >> 6, u = t & 63;
    int kslot = u >> 4, cl = u & 15;
    int k0 = kch * 32 + kslot * 8;
    s8v v = *(const s8v*)(buf + cl * 136 + k0);
    *(s8v*)(pairF + ((size_t)pb * 256 + t) * 8) = v;
  } else {
    int bid = bx - 4328;
    int lane = t & 63, wid = t >> 6;
    int row0 = bid * 16;
    const float4 gv = ((const float4*)ln_g)[lane];
    const float4 bv = ((const float4*)ln_b)[lane];
    #pragma unroll
    for (int rr = 0; rr < 4; ++rr) {
      int row = row0 + wid * 4 + rr;
      float4 v = ((const float4*)(msa + (size_t)row * DM))[lane];
      float s = v.x + v.y + v.z + v.w;
      float q = v.x * v.x + v.y * v.y + v.z * v.z + v.w * v.w;
      #pragma unroll
      for (int off = 32; off; off >>= 1) { s += __shfl_down(s, off); q += __shfl_down(q, off); }
      s = __shfl(s, 0); q = __shfl(q, 0);
      float mean = s * (1.f / DM);
      float var  = q * (1.f / DM) - mean * mean;
      float rstd = rsqrtf(var + 1e-5f);
      s4v o;
      o[0] = (short)f2bf((v.x - mean) * rstd * gv.x + bv.x);
      o[1] = (short)f2bf((v.y - mean) * rstd * gv.y + bv.y);
      o[2] = (short)f2bf((v.z - mean) * rstd * gv.z + bv.z);
      o[3] = (short)f2bf((v.w - mean) * rstd * gv.w + bv.w);
      *(s4v*)(buf + (wid * 4 + rr) * 264 + lane * 4) = o;
    }
    __syncthreads();
    #pragma unroll
    for (int it = 0; it < 2; ++it) {
      int o = it * 256 + t;
      int kch = o >> 6, kslot = (o >> 4) & 3, rr = o & 15;
      int k0 = kch * 32 + kslot * 8;
      s8v v = *(const s8v*)(buf + rr * 264 + k0);
      *(s8v*)(msaF + (size_t)bid * 4096 + (size_t)o * 8) = v;
    }
  }
}

// ---------------------------------------------------------------------------
// K2: msaF @ WlrF -> leftT/rightT bf16.
// ---------------------------------------------------------------------------
__global__ __launch_bounds__(256) void k_gemm_lr(const u16* __restrict__ msaF,
                                                 const u16* __restrict__ WlrF,
                                                 const float* __restrict__ bl,
                                                 const float* __restrict__ br,
                                                 u16* __restrict__ leftT,
                                                 u16* __restrict__ rightT)
{
  int lane = threadIdx.x & 63, wid = threadIdx.x >> 6;
  int sIdx = blockIdx.x;
  f4v acc[4][4] = {};
  #pragma unroll
  for (int ks = 0; ks < 8; ++ks) {
    s8v a[4], bb[4];
    #pragma unroll
    for (int mi = 0; mi < 4; ++mi)
      a[mi] = *(const s8v*)(msaF + ((size_t)(sIdx * 16 + wid * 4 + mi) * 8 + ks) * 512 + lane * 8);
    #pragma unroll
    for (int ni = 0; ni < 4; ++ni)
      bb[ni] = *(const s8v*)(WlrF + ((size_t)(ni * 8 + ks)) * 512 + lane * 8);
    #pragma unroll
    for (int mi = 0; mi < 4; ++mi)
      #pragma unroll
      for (int ni = 0; ni < 4; ++ni)
        acc[mi][ni] = MFMA(a[mi], bb[ni], acc[mi][ni]);
  }
  #pragma unroll
  for (int mi = 0; mi < 4; ++mi) {
    #pragma unroll
    for (int ni = 0; ni < 4; ++ni) {
      int n = ni * 16 + (lane & 15);
      #pragma unroll
      for (int r = 0; r < 4; ++r) {
        int l = wid * 64 + mi * 16 + (lane >> 4) * 4 + r;
        float v = acc[mi][ni][r];
        if (n < 32) {
          leftT[((size_t)l * 32 + n) * 128 + sIdx] = f2bf(v + bl[n]);
        } else {
          rightT[((size_t)l * 32 + (n - 32)) * 128 + sIdx] =
              f2bf((v + br[n - 32]) * (1.f / NS));
        }
      }
    }
  }
}

// ---------------------------------------------------------------------------
// K3: fragpack -> leftF / rightF fragment tiles. grid 256.
// ---------------------------------------------------------------------------
__global__ __launch_bounds__(256) void k_fragpack(const u16* __restrict__ leftT,
                                                  const u16* __restrict__ rightT,
                                                  u16* __restrict__ leftF,
                                                  u16* __restrict__ rightF)
{
  __shared__ alignas(16) u16 lds[64 * 136];
  int t = threadIdx.x, bx = blockIdx.x;
  bool isR = bx >= 128;
  int blk = isR ? (bx - 128) : bx;
  #pragma unroll
  for (int it = 0; it < 4; ++it) {
    int u = it * 256 + t;
    int row = u >> 4, sc = u & 15;
    const u16* src;
    if (!isR) {
      src = leftT + ((size_t)(blk * 64 + row)) * 128 + sc * 8;
    } else {
      int gcol = blk * 64 + row;
      int mg = gcol >> 10, rem = gcol & 1023;
      int jc = rem >> 8, nc = rem & 255;
      int m = mg * 32 + (nc >> 3), j = jc * 8 + (nc & 7);
      src = rightT + ((size_t)(m * 32 + j)) * 128 + sc * 8;
    }
    *(s8v*)(lds + row * 136 + sc * 8) = *(const s8v*)src;
  }
  __syncthreads();
  u16* dst = (isR ? rightF : leftF) + (size_t)blk * 8192;
  #pragma unroll
  for (int it = 0; it < 4; ++it) {
    int o = it * 256 + t;
    int tloc = o >> 6, u = o & 63;
    int rb = tloc >> 2, sc2 = tloc & 3;
    int kslot = u >> 4, rr = u & 15;
    int row = rb * 16 + rr, s0 = sc2 * 32 + kslot * 8;
    *(s8v*)(dst + (size_t)o * 8) = *(const s8v*)(lds + row * 136 + s0);
  }
}

// ---------------------------------------------------------------------------
// K4: fused outer-product + Wo-proj + proj_down (R12 single-buffer + XCD).
// ---------------------------------------------------------------------------
__global__ __launch_bounds__(512, 4) void k_fused(
    const u16* __restrict__ leftF, const u16* __restrict__ rightF,
    const u16* __restrict__ WoF, const u16* __restrict__ pairF,
    const u16* __restrict__ WdF, const float* __restrict__ bo,
    const float* __restrict__ bd, u16* __restrict__ pN)
{
  __shared__ alignas(16) u16 Als[8192];    // 16 KB
  __shared__ alignas(16) u16 opL[16384];   // 32 KB
  __shared__ alignas(16) u16 obL[8192];    // 16 KB
  int t = threadIdx.x, lane = t & 63, w = t >> 6;
  int rlo = lane & 15, slot = lane >> 4;
  int b = blockIdx.x;
  int mg = b & 7, lp = b >> 3;             // XCD swizzle (1024 % 8 == 0)
  int l0 = lp * 2, m0 = mg * 32;

  #pragma unroll
  for (int i = 0; i < 2; ++i) {
    int u = t + 512 * i;
    *(s8v*)(Als + (size_t)u * 8) = *(const s8v*)(leftF + (size_t)lp * 8192 + (size_t)u * 8);
  }

  f4v acc2[4] = {};
  s8v bb[8];
  #pragma unroll
  for (int ks = 0; ks < 4; ++ks)
    #pragma unroll
    for (int ni = 0; ni < 2; ++ni)
      bb[ks * 2 + ni] = *(const s8v*)(rightF +
          ((size_t)((mg * 64 + 0 * 16 + w * 2 + ni) * 4 + ks)) * 512 + lane * 8);
  __syncthreads();

  #pragma unroll
  for (int jc = 0; jc < 4; ++jc) {
    f4v acc1[4][2] = {};
    __builtin_amdgcn_s_setprio(1);
    #pragma unroll
    for (int ks = 0; ks < 4; ++ks) {
      s8v a[4];
      #pragma unroll
      for (int mi = 0; mi < 4; ++mi)
        a[mi] = *(const s8v*)(Als + (size_t)(mi * 4 + ks) * 512 + lane * 8);
      #pragma unroll
      for (int mi = 0; mi < 4; ++mi)
        #pragma unroll
        for (int ni = 0; ni < 2; ++ni)
          acc1[mi][ni] = MFMA(a[mi], bb[ks * 2 + ni], acc1[mi][ni]);
    }
    __builtin_amdgcn_s_setprio(0);
    #pragma unroll
    for (int mi = 0; mi < 4; ++mi) {
      int i0 = (mi & 1) * 16 + slot * 4;
      int lLoc = mi >> 1;
      int kslot = (i0 >> 3) & 3;
      #pragma unroll
      for (int ni = 0; ni < 2; ++ni) {
        int n = w * 32 + ni * 16 + rlo;
        int pix = lLoc * 32 + (n >> 3);
        int jj = n & 7;
        uint2 o2;
        o2.x = cvtpk2(acc1[mi][ni][0], acc1[mi][ni][1]);
        o2.y = cvtpk2(acc1[mi][ni][2], acc1[mi][ni][3]);
        int byte = ((pix >> 4) * 8 + jj) * 1024 +
                   (kslot * 16 + ((pix & 15) ^ jj)) * 16 + (i0 & 7) * 2;
        *(uint2*)((char*)opL + byte) = o2;
      }
    }
    s8v wb[8];
    #pragma unroll
    for (int ks = 0; ks < 8; ++ks)
      wb[ks] = *(const s8v*)(WoF + ((size_t)(w * 32 + jc * 8 + ks)) * 512 + lane * 8);
    __syncthreads();
    __builtin_amdgcn_s_setprio(1);
    #pragma unroll
    for (int ks = 0; ks < 8; ++ks) {
      s8v a[4];
      #pragma unroll
      for (int mi = 0; mi < 4; ++mi) {
        int byte = (mi * 8 + ks) * 1024 + (slot * 16 + (rlo ^ ks)) * 16;
        a[mi] = *(const s8v*)((const char*)opL + byte);
      }
      #pragma unroll
      for (int mi = 0; mi < 4; ++mi)
        acc2[mi] = MFMA(a[mi], wb[ks], acc2[mi]);
    }
    __builtin_amdgcn_s_setprio(0);
    if (jc < 3) {
      #pragma unroll
      for (int ks = 0; ks < 4; ++ks)
        #pragma unroll
        for (int ni = 0; ni < 2; ++ni)
          bb[ks * 2 + ni] = *(const s8v*)(rightF +
              ((size_t)((mg * 64 + (jc + 1) * 16 + w * 2 + ni) * 4 + ks)) * 512 + lane * 8);
    }
    __syncthreads();
  }

  {
    int c = w * 16 + rlo;
    float bias = bo[c];
    #pragma unroll
    for (int mi = 0; mi < 4; ++mi)
      #pragma unroll
      for (int r = 0; r < 4; ++r) {
        int pix = mi * 16 + slot * 4 + r;
        int byte = (pix * 256 + c * 2) ^ ((pix & 7) << 4);
        *(u16*)((char*)obL + byte) = f2bf(acc2[mi][r] + bias);
      }
  }
  __syncthreads();

  int wr = w >> 2, wcq = w & 3;
  int pix0 = wr * 32, c0 = wcq * 32;
  {
    f4v acc[2][2] = {};
    #pragma unroll
    for (int ks = 0; ks < 4; ++ks) {        // K 0..127 from pairF
      s8v a[2], b2[2];
      #pragma unroll
      for (int mi = 0; mi < 2; ++mi) {
        int pb = (l0 + wr) * 16 + (m0 >> 4) + mi;
        a[mi] = *(const s8v*)(pairF + ((size_t)(pb * 4 + ks)) * 512 + lane * 8);
      }
      #pragma unroll
      for (int ni = 0; ni < 2; ++ni) {
        int cblk = wcq * 2 + ni;
        b2[ni] = *(const s8v*)(WdF + ((size_t)(cblk * 8 + ks)) * 512 + lane * 8);
      }
      #pragma unroll
      for (int mi = 0; mi < 2; ++mi)
        #pragma unroll
        for (int ni = 0; ni < 2; ++ni)
          acc[mi][ni] = MFMA(a[mi], b2[ni], acc[mi][ni]);
    }
    #pragma unroll
    for (int ks = 0; ks < 4; ++ks) {        // K 128..255 from obL
      s8v a[2], b2[2];
      #pragma unroll
      for (int mi = 0; mi < 2; ++mi) {
        int pix = pix0 + mi * 16 + rlo;
        int k = ks * 32 + slot * 8;
        int byte = (pix * 256 + k * 2) ^ ((pix & 7) << 4);
        a[mi] = *(const s8v*)((const char*)obL + byte);
      }
      #pragma unroll
      for (int ni = 0; ni < 2; ++ni) {
        int cblk = wcq * 2 + ni;
        b2[ni] = *(const s8v*)(WdF + ((size_t)(cblk * 8 + 4 + ks)) * 512 + lane * 8);
      }
      #pragma unroll
      for (int mi = 0; mi < 2; ++mi)
        #pragma unroll
        for (int ni = 0; ni < 2; ++ni)
          acc[mi][ni] = MFMA(a[mi], b2[ni], acc[mi][ni]);
    }
    #pragma unroll
    for (int mi = 0; mi < 2; ++mi)
      #pragma unroll
      for (int ni = 0; ni < 2; ++ni) {
        int c = c0 + ni * 16 + rlo;
        float bias = bd[c];
        #pragma unroll
        for (int r = 0; r < 4; ++r) {
          int pix = pix0 + mi * 16 + slot * 4 + r;
          int byte = (pix * 256 + c * 2) ^ ((pix & 7) << 4);
          *(u16*)((char*)opL + byte) = f2bf(acc[mi][ni][r] + bias);
        }
      }
  }
  __syncthreads();

  #pragma unroll
  for (int q = 0; q < 2; ++q) {
    int u = q * 512 + t;
    int pix = u >> 4, off = u & 15;
    int byte = (pix * 256 + off * 16) ^ ((pix & 7) << 4);
    uint4 v = *(const uint4*)((const char*)opL + byte);
    int pixG = (l0 + (pix >> 5)) * 256 + m0 + (pix & 31);
    *(uint4*)(pN + (size_t)pixG * 128 + off * 8) = v;
  }
}

// ---------------------------------------------------------------------------
// K5: conv3x3 implicit-GEMM MFMA, 3-ROW staging (1 output row/block) for
// 3 blocks/CU (3 waves/SIMD, +50% TLP vs R18). 4 waves x (64 px x 32 co),
// B-frags loaded once per block (no redundancy). partS/partQ/red2 alias the
// staged-tile LDS (phase-disjoint; barriers reordered). grid 1024.
// ---------------------------------------------------------------------------
#define CLOADB(s, B) {                                                        \
    _Pragma("unroll")                                                         \
    for (int j = 0; j < 2; ++j) {                                             \
      const int st_ = (s) + j;                                                \
      _Pragma("unroll")                                                       \
      for (int ni = 0; ni < 2; ++ni) {                                        \
        int co_ = co0 + ni * 16 + rlo;                                        \
        B[j][ni] = *(const s8v*)(wP +                                         \
            ((size_t)(st_ * 128 + co_) * 4 + slot) * 8);                      \
      }                                                                       \
    } }
#define CSTEP2(s, B) {                                                        \
    _Pragma("unroll")                                                         \
    for (int j = 0; j < 2; ++j) {                                             \
      const int st_ = (s) + j, tap_ = st_ >> 2, kk_ = st_ & 3;                \
      const int dy_ = tap_ / 3, dx_ = tap_ % 3;                               \
      s8v a_[4];                                                              \
      _Pragma("unroll")                                                       \
      for (int mi = 0; mi < 4; ++mi) {                                        \
        int p_ = mi * 16 + rlo + dx_;                                         \
        int lb_ = (((dy_) * 66 + p_) * 256 + kk_ * 64 + slot * 16) ^          \
                  ((p_ & 7) << 4);                                            \
        a_[mi] = *(const s8v*)((const char*)Ast + lb_);                       \
      }                                                                       \
      __builtin_amdgcn_s_setprio(1);                                          \
      _Pragma("unroll")                                                       \
      for (int mi = 0; mi < 4; ++mi)                                          \
        _Pragma("unroll")                                                     \
        for (int ni = 0; ni < 2; ++ni)                                        \
          acc[mi][ni] = MFMA(a_[mi], B[j][ni], acc[mi][ni]);                  \
      __builtin_amdgcn_s_setprio(0);                                          \
    } }

template<bool FUSE_IN>
__global__ __launch_bounds__(256, 3) void k_conv(const u16* __restrict__ inN,
                                                 const float* __restrict__ gSin,
                                                 const float* __restrict__ gQin,
                                                 const float* __restrict__ ing,
                                                 const float* __restrict__ inb,
                                                 const u16* __restrict__ wP,
                                                 u16* __restrict__ outB,
                                                 float* __restrict__ gSout,
                                                 float* __restrict__ gQout)
{
  // 50688 B staged tile; epilogue reuses [0,32768) as f32 out, [32768,...)
  // as partS/partQ; prologue red2 also aliases (dead before staging).
  __shared__ alignas(16) u16 Ast[3 * 66 * 128];
  __shared__ alignas(16) float sstat[256];
  int t = threadIdx.x, lane = t & 63, w = t >> 6;
  int rlo = lane & 15, slot = lane >> 4;
  int b = blockIdx.x;
  int L = (b & 7) * 128 + (b >> 3);              // XCD swizzle (1024 % 8 == 0)
  int xt = L & 3, y0 = L >> 2;
  int x0 = xt * 64;
  float* partS = (float*)((char*)Ast + 32768);   // 128 floats
  float* partQ = partS + 128;                    // 128 floats
  float* red2  = partQ + 128;                    // 512 floats (prologue only)

  if constexpr (FUSE_IN) {
    int c = t & 127, h = t >> 7;
    float s = 0.f, q = 0.f;
    for (int i = h * 512; i < h * 512 + 512; ++i) {
      s += gSin[(size_t)i * 128 + c];
      q += gQin[(size_t)i * 128 + c];
    }
    red2[h * 128 + c] = s; red2[256 + h * 128 + c] = q;
    __syncthreads();
    if (t < 128) {
      float ss = red2[t] + red2[128 + t];
      float qq = red2[256 + t] + red2[384 + t];
      float m = ss * (1.f / HW);
      float var = qq * (1.f / HW) - m * m;
      float rstd = rsqrtf(var + 1e-6f);
      float sc = rstd * ing[t];
      sstat[t] = sc;
      sstat[128 + t] = inb[t] - m * sc;
    }
    __syncthreads();
  }

  for (int u = t; u < 3168; u += 256) {          // 3 rows x 66 px x 16 units
    int r = u / 1056;
    int rem = u - r * 1056;
    int p = rem >> 4, ku = rem & 15;
    int gy = y0 + r - 1, gx = x0 - 1 + p;
    s8v v = zero8();
    if ((unsigned)gy < 256u && (unsigned)gx < 256u) {
      v = *(const s8v*)(inN + ((size_t)gy * LL + gx) * 128 + ku * 8);
      if constexpr (FUSE_IN) {
        float4 s0 = ((const float4*)sstat)[ku * 2];
        float4 s1 = ((const float4*)sstat)[ku * 2 + 1];
        float4 q0 = ((const float4*)(sstat + 128))[ku * 2];
        float4 q1 = ((const float4*)(sstat + 128))[ku * 2 + 1];
        float f0 = elu1(bf2f((u16)v[0]) * s0.x + q0.x);
        float f1 = elu1(bf2f((u16)v[1]) * s0.y + q0.y);
        float f2 = elu1(bf2f((u16)v[2]) * s0.z + q0.z);
        float f3 = elu1(bf2f((u16)v[3]) * s0.w + q0.w);
        float f4 = elu1(bf2f((u16)v[4]) * s1.x + q1.x);
        float f5 = elu1(bf2f((u16)v[5]) * s1.y + q1.y);
        float f6 = elu1(bf2f((u16)v[6]) * s1.z + q1.z);
        float f7 = elu1(bf2f((u16)v[7]) * s1.w + q1.w);
        uint4 uv;
        uv.x = cvtpk2(f0, f1); uv.y = cvtpk2(f2, f3);
        uv.z = cvtpk2(f4, f5); uv.w = cvtpk2(f6, f7);
        v = __builtin_bit_cast(s8v, uv);
      }
    }
    int lb = (u * 16) ^ ((p & 7) << 4);
    *(s8v*)((char*)Ast + lb) = v;
  }
  __syncthreads();
  int co0 = w * 32;                              // wave owns 32-channel slice
  f4v acc[4][2] = {};
  s8v bA[2][2], bB[2][2];
  CLOADB(0, bA)
  #pragma unroll
  for (int s = 0; s < 36; s += 4) {
    CLOADB(s + 2, bB)
    CSTEP2(s, bA)
    if (s + 4 < 36) { CLOADB(s + 4, bA) }
    CSTEP2(s + 2, bB)
  }
  // IN partial stats (registers only; LDS writes deferred past the barrier)
  float sreg[2], qreg[2];
  #pragma unroll
  for (int ni = 0; ni < 2; ++ni) {
    float s = 0.f, q = 0.f;
    #pragma unroll
    for (int mi = 0; mi < 4; ++mi)
      #pragma unroll
      for (int r = 0; r < 4; ++r) {
        float v = acc[mi][ni][r];
        s += v; q += v * v;
      }
    s += __shfl_xor(s, 16); s += __shfl_xor(s, 32);
    q += __shfl_xor(q, 16); q += __shfl_xor(q, 32);
    sreg[ni] = s; qreg[ni] = q;
  }
  __syncthreads();           // all Ast reads done; safe to reuse whole region
  if (slot == 0) {
    #pragma unroll
    for (int ni = 0; ni < 2; ++ni) {
      partS[co0 + ni * 16 + rlo] = sreg[ni];
      partQ[co0 + ni * 16 + rlo] = qreg[ni];
    }
  }
  float* AstF = (float*)Ast; // [64 px][128 co] f32, XOR (pix&7)<<4 (32 KB)
  #pragma unroll
  for (int mi = 0; mi < 4; ++mi)
    #pragma unroll
    for (int ni = 0; ni < 2; ++ni) {
      int co = co0 + ni * 16 + rlo;
      #pragma unroll
      for (int r = 0; r < 4; ++r) {
        int pix = mi * 16 + slot * 4 + r;
        int byte = (pix * 512 + co * 4) ^ ((pix & 7) << 4);
        *(float*)((char*)AstF + byte) = acc[mi][ni][r];
      }
    }
  __syncthreads();
  if (t < 128) {
    gSout[(size_t)b * 128 + t] = partS[t];
    gQout[(size_t)b * 128 + t] = partQ[t];
  }
  #pragma unroll
  for (int it = 0; it < 4; ++it) {
    int u = it * 256 + t;                   // 1024 units of 8 channels
    int pix = u >> 4, cv8 = u & 15;
    int b0b = (pix * 512 + cv8 * 32) ^ ((pix & 7) << 4);
    int b1b = (pix * 512 + cv8 * 32 + 16) ^ ((pix & 7) << 4);
    float4 a = *(const float4*)((const char*)AstF + b0b);
    float4 bv = *(const float4*)((const char*)AstF + b1b);
    uint4 o;
    o.x = cvtpk2(a.x, a.y); o.y = cvtpk2(a.z, a.w);
    o.z = cvtpk2(bv.x, bv.y); o.w = cvtpk2(bv.z, bv.w);
    *(uint4*)(outB + ((size_t)y0 * LL + x0 + pix) * 128 + cv8 * 8) = o;
  }
}

// ---------------------------------------------------------------------------
// K6: PARALLEL stats reduce: one block per channel (grid 128, block 512),
// 1024 partials/channel (2 per thread).
// ---------------------------------------------------------------------------
__global__ __launch_bounds__(512) void k_instat2(const float* __restrict__ gS,
                                                 const float* __restrict__ gQ,
                                                 const float* __restrict__ g,
                                                 const float* __restrict__ b,
                                                 float* __restrict__ st)
{
  __shared__ float redS[8], redQ[8];
  int c = blockIdx.x, t = threadIdx.x;
  int lane = t & 63, w = t >> 6;
  float s = gS[(size_t)t * 128 + c] + gS[(size_t)(t + 512) * 128 + c];
  float q = gQ[(size_t)t * 128 + c] + gQ[(size_t)(t + 512) * 128 + c];
  #pragma unroll
  for (int off = 32; off; off >>= 1) {
    s += __shfl_down(s, off);
    q += __shfl_down(q, off);
  }
  if (lane == 0) { redS[w] = s; redQ[w] = q; }
  __syncthreads();
  if (t == 0) {
    float ss = 0.f, qq = 0.f;
    #pragma unroll
    for (int i = 0; i < 8; ++i) { ss += redS[i]; qq += redQ[i]; }
    float m = ss * (1.f / HW);
    float var = qq * (1.f / HW) - m * m;
    float rstd = rsqrtf(var + 1e-6f);
    float sc = rstd * g[c];
    st[c] = sc;
    st[128 + c] = b[c] - m * sc;
  }
}

// ---------------------------------------------------------------------------
// K7: out = elu(pN + IN2(h2raw)); 8-ch units. grid 4096.
// ---------------------------------------------------------------------------
__global__ __launch_bounds__(256) void k_final(const u16* __restrict__ pN,
                                               const u16* __restrict__ h2,
                                               const float* __restrict__ st,
                                               float* __restrict__ out)
{
  int i = blockIdx.x * 256 + threadIdx.x;   // 1,048,576 uint4 units
  int c8 = i & 15;
  uint4 hv = ((const uint4*)h2)[i];
  uint4 pv = ((const uint4*)pN)[i];
  float4 s0 = ((const float4*)st)[c8 * 2], s1 = ((const float4*)st)[c8 * 2 + 1];
  float4 q0 = ((const float4*)(st + 128))[c8 * 2], q1 = ((const float4*)(st + 128))[c8 * 2 + 1];
  float4 f0, f1;
  f0.x = bf2f((u16)(hv.x & 0xffff)) * s0.x + q0.x + bf2f((u16)(pv.x & 0xffff));
  f0.y = bf2f((u16)(hv.x >> 16))    * s0.y + q0.y + bf2f((u16)(pv.x >> 16));
  f0.z = bf2f((u16)(hv.y & 0xffff)) * s0.z + q0.z + bf2f((u16)(pv.y & 0xffff));
  f0.w = bf2f((u16)(hv.y >> 16))    * s0.w + q0.w + bf2f((u16)(pv.y >> 16));
  f1.x = bf2f((u16)(hv.z & 0xffff)) * s1.x + q1.x + bf2f((u16)(pv.z & 0xffff));
  f1.y = bf2f((u16)(hv.z >> 16))    * s1.y + q1.y + bf2f((u16)(pv.z >> 16));
  f1.z = bf2f((u16)(hv.w & 0xffff)) * s1.z + q1.z + bf2f((u16)(pv.w & 0xffff));
  f1.w = bf2f((u16)(hv.w >> 16))    * s1.w + q1.w + bf2f((u16)(pv.w >> 16));
  f0.x = elu1(f0.x); f0.y = elu1(f0.y); f0.z = elu1(f0.z); f0.w = elu1(f0.w);
  f1.x = elu1(f1.x); f1.y = elu1(f1.y); f1.z = elu1(f1.z); f1.w = elu1(f1.w);
  ((float4*)out)[(size_t)i * 2]     = f0;
  ((float4*)out)[(size_t)i * 2 + 1] = f1;
}

// ---------------------------------------------------------------------------
extern "C" void kernel_launch(void* const* d_in, const int* in_sizes, int n_in,
                              void* d_out, int out_size, void* d_ws, size_t ws_size,
                              hipStream_t stream)
{
  const float* msa   = (const float*)d_in[0];
  const float* pair  = (const float*)d_in[1];
  const float* ln_g  = (const float*)d_in[2];
  const float* ln_b  = (const float*)d_in[3];
  const float* Wl    = (const float*)d_in[4];
  const float* bl    = (const float*)d_in[5];
  const float* Wr    = (const float*)d_in[6];
  const float* br    = (const float*)d_in[7];
  const float* Wo    = (const float*)d_in[8];
  const float* bo    = (const float*)d_in[9];
  const float* Wd    = (const float*)d_in[10];
  const float* bd    = (const float*)d_in[11];
  const float* conv1 = (const float*)d_in[12];
  const float* in1_g = (const float*)d_in[13];
  const float* in1_b = (const float*)d_in[14];
  const float* conv2 = (const float*)d_in[15];
  const float* in2_g = (const float*)d_in[16];
  const float* in2_b = (const float*)d_in[17];
  float* out = (float*)d_out;

  // Workspace (F = 1Mi floats = 4 MB), peak ~91 MB.
  float* ws = (float*)d_ws;
  const size_t F = 1048576;
  u16* msaF   = (u16*)ws;
  u16* leftT  = (u16*)(ws + 4 * F);
  u16* rightT = (u16*)(ws + 4 * F + F / 2);
  u16* leftF  = (u16*)(ws + 5 * F);
  u16* rightF = (u16*)(ws + 5 * F + F / 2);
  u16* pN     = (u16*)(ws + 6 * F);
  u16* h1raw  = (u16*)(ws + 10 * F);
  u16* h2raw  = (u16*)(ws + 14 * F);
  u16* pairF  = (u16*)(ws + 18 * F);
  float* gS1  = ws + 22 * F;                 // 131072 floats (1024 x 128)
  float* gQ1  = ws + 22 * F + 131072;
  float* gS2  = ws + 22 * F + 262144;
  float* gQ2  = ws + 22 * F + 393216;
  float* stats = ws + 22 * F + 524288;       // 256
  u16* aux    = (u16*)(ws + 22 * F + 524544);
  u16* wP1    = aux;                         // 147456
  u16* wP2    = aux + 147456;                // 147456
  u16* WoF    = aux + 294912;                // 131072
  u16* WdF    = aux + 425984;                // 32768
  u16* WlrF   = aux + 458752;                // 16384

  k_prep_ln<<<dim3(6376), dim3(256), 0, stream>>>(Wl, Wr, Wo, Wd, conv1, conv2,
                                                  pair, msa, ln_g, ln_b,
                                                  WlrF, WoF, WdF, wP1, wP2, pairF, msaF);
  k_gemm_lr<<<dim3(128), dim3(256), 0, stream>>>(msaF, WlrF, bl, br, leftT, rightT);
  k_fragpack<<<dim3(256), dim3(256), 0, stream>>>(leftT, rightT, leftF, rightF);

  k_fused<<<dim3(1024), dim3(512), 0, stream>>>(leftF, rightF, WoF, pairF, WdF,
                                                bo, bd, pN);

  k_conv<false><<<dim3(1024), dim3(256), 0, stream>>>(pN, nullptr, nullptr,
                                                      nullptr, nullptr,
                                                      wP1, h1raw, gS1, gQ1);
  k_conv<true><<<dim3(1024), dim3(256), 0, stream>>>(h1raw, gS1, gQ1, in1_g, in1_b,
                                                     wP2, h2raw, gS2, gQ2);
  k_instat2<<<dim3(128), dim3(512), 0, stream>>>(gS2, gQ2, in2_g, in2_b, stats);

  k_final<<<dim3(4096), dim3(256), 0, stream>>>(pN, h2raw, stats, out);
}

// Round 20
// 179.436 us; speedup vs baseline: 2.4863x; 2.4863x over previous
//
#include <hip/hip_runtime.h>
#include <math.h>

#define LL 256      // L
#define NS 128      // N sequences
#define DM 256      // d_msa
#define DH 32       // d_h
#define DP 128      // d_pair
#define HW 65536    // L*L

using u16 = unsigned short;
typedef __attribute__((ext_vector_type(8))) short s8v;   // 8 bf16 (A/B frag)
typedef __attribute__((ext_vector_type(4))) short s4v;   // 4 bf16
typedef __attribute__((ext_vector_type(4))) float f4v;   // C/D frag

#define MFMA(a, b, c) __builtin_amdgcn_mfma_f32_16x16x32_bf16((a), (b), (c), 0, 0, 0)

__device__ __forceinline__ u16 f2bf(float f) {
  unsigned u = __float_as_uint(f);
  u = (u + 0x7FFFu + ((u >> 16) & 1u)) >> 16;   // RNE
  return (u16)u;
}
__device__ __forceinline__ unsigned cvtpk2(float lo, float hi) {
  unsigned r;
  asm("v_cvt_pk_bf16_f32 %0, %1, %2" : "=v"(r) : "v"(lo), "v"(hi));
  return r;
}
__device__ __forceinline__ float bf2f(u16 h) { return __uint_as_float(((unsigned)h) << 16); }
__device__ __forceinline__ float elu1(float v) { return v > 0.f ? v : expm1f(v); }
__device__ __forceinline__ s8v zero8() {
  s8v v;
  #pragma unroll
  for (int j = 0; j < 8; ++j) v[j] = 0;
  return v;
}

// Fragment-tile layout: 1 KB tile = 16 rows x 32 k (bf16).
// unit(16B) = ((k>>3)&3)*16 + (row&15) ; elem = k&7.
// Wave fragment load = tile_base + lane*16 (fully coalesced).

// ---------------------------------------------------------------------------
// P: weight preps (fragment-tiled) + pairF + LayerNorm->msaF, one launch.
// ---------------------------------------------------------------------------
__device__ __forceinline__ void prep_convw(const float* __restrict__ w,
                                           u16* __restrict__ wP, int idx)
{
  int h = idx & 3, co = (idx >> 2) & 127, kk = (idx >> 9) & 3, tap = idx >> 11;
  s8v o;
  #pragma unroll
  for (int j = 0; j < 8; ++j) {
    int ci = kk * 32 + h * 8 + j;
    o[j] = (short)f2bf(w[((size_t)co * DP + ci) * 9 + tap]);
  }
  *(s8v*)(wP + (size_t)idx * 8) = o;
}

__global__ __launch_bounds__(256) void k_prep_ln(
    const float* __restrict__ Wl, const float* __restrict__ Wr,
    const float* __restrict__ Wo, const float* __restrict__ Wd,
    const float* __restrict__ conv1, const float* __restrict__ conv2,
    const float* __restrict__ pair,
    const float* __restrict__ msa, const float* __restrict__ ln_g,
    const float* __restrict__ ln_b,
    u16* __restrict__ WlrF, u16* __restrict__ WoF, u16* __restrict__ WdF,
    u16* __restrict__ wP1, u16* __restrict__ wP2, u16* __restrict__ pairF,
    u16* __restrict__ msaF)
{
  __shared__ alignas(16) u16 buf[16 * 264];
  int bx = blockIdx.x, t = threadIdx.x;
  if (bx < 64) {
    int o = bx * 256 + t;
    int tile = o >> 6, u = o & 63;
    int cblk = tile >> 5, j = tile & 31;
    int kslot = u >> 4, cl = u & 15;
    int c = cblk * 16 + cl;
    s8v v;
    #pragma unroll
    for (int e = 0; e < 8; ++e) {
      int i = kslot * 8 + e;
      v[e] = (short)f2bf(Wo[(size_t)(i * 32 + j) * DP + c]);
    }
    *(s8v*)(WoF + (size_t)o * 8) = v;
  } else if (bx < 80) {
    int o = (bx - 64) * 256 + t;
    int tile = o >> 6, u = o & 63;
    int cblk = tile >> 3, kch = tile & 7;
    int kslot = u >> 4, cl = u & 15;
    int c = cblk * 16 + cl;
    s8v v;
    #pragma unroll
    for (int e = 0; e < 8; ++e) {
      int k = kch * 32 + kslot * 8 + e;
      v[e] = (short)f2bf(Wd[(size_t)k * DP + c]);
    }
    *(s8v*)(WdF + (size_t)o * 8) = v;
  } else if (bx < 88) {
    int o = (bx - 80) * 256 + t;
    int tile = o >> 6, u = o & 63;
    int nblk = tile >> 3, kch = tile & 7;
    int kslot = u >> 4, cl = u & 15;
    int n = nblk * 16 + cl;
    s8v v;
    #pragma unroll
    for (int e = 0; e < 8; ++e) {
      int k = kch * 32 + kslot * 8 + e;
      float x = (n < 32) ? Wl[k * DH + n] : Wr[k * DH + (n - 32)];
      v[e] = (short)f2bf(x);
    }
    *(s8v*)(WlrF + (size_t)o * 8) = v;
  } else if (bx < 160) {
    prep_convw(conv1, wP1, (bx - 88) * 256 + t);
  } else if (bx < 232) {
    prep_convw(conv2, wP2, (bx - 160) * 256 + t);
  } else if (bx < 4328) {
    int pb = bx - 232;
    #pragma unroll
    for (int it = 0; it < 2; ++it) {
      int idx = it * 256 + t;
      int pix = idx >> 5, f4i = idx & 31;
      float4 v = ((const float4*)pair)[(size_t)(pb * 16 + pix) * 32 + f4i];
      s4v o;
      o[0] = (short)f2bf(v.x); o[1] = (short)f2bf(v.y);
      o[2] = (short)f2bf(v.z); o[3] = (short)f2bf(v.w);
      *(s4v*)(buf + pix * 136 + f4i * 4) = o;
    }
    __syncthreads();
    int kch = t >> 6, u = t & 63;
    int kslot = u >> 4, cl = u & 15;
    int k0 = kch * 32 + kslot * 8;
    s8v v = *(const s8v*)(buf + cl * 136 + k0);
    *(s8v*)(pairF + ((size_t)pb * 256 + t) * 8) = v;
  } else {
    int bid = bx - 4328;
    int lane = t & 63, wid = t >> 6;
    int row0 = bid * 16;
    const float4 gv = ((const float4*)ln_g)[lane];
    const float4 bv = ((const float4*)ln_b)[lane];
    #pragma unroll
    for (int rr = 0; rr < 4; ++rr) {
      int row = row0 + wid * 4 + rr;
      float4 v = ((const float4*)(msa + (size_t)row * DM))[lane];
      float s = v.x + v.y + v.z + v.w;
      float q = v.x * v.x + v.y * v.y + v.z * v.z + v.w * v.w;
      #pragma unroll
      for (int off = 32; off; off >>= 1) { s += __shfl_down(s, off); q += __shfl_down(q, off); }
      s = __shfl(s, 0); q = __shfl(q, 0);
      float mean = s * (1.f / DM);
      float var  = q * (1.f / DM) - mean * mean;
      float rstd = rsqrtf(var + 1e-5f);
      s4v o;
      o[0] = (short)f2bf((v.x - mean) * rstd * gv.x + bv.x);
      o[1] = (short)f2bf((v.y - mean) * rstd * gv.y + bv.y);
      o[2] = (short)f2bf((v.z - mean) * rstd * gv.z + bv.z);
      o[3] = (short)f2bf((v.w - mean) * rstd * gv.w + bv.w);
      *(s4v*)(buf + (wid * 4 + rr) * 264 + lane * 4) = o;
    }
    __syncthreads();
    #pragma unroll
    for (int it = 0; it < 2; ++it) {
      int o = it * 256 + t;
      int kch = o >> 6, kslot = (o >> 4) & 3, rr = o & 15;
      int k0 = kch * 32 + kslot * 8;
      s8v v = *(const s8v*)(buf + rr * 264 + k0);
      *(s8v*)(msaF + (size_t)bid * 4096 + (size_t)o * 8) = v;
    }
  }
}

// ---------------------------------------------------------------------------
// K2: msaF @ WlrF -> leftT/rightT bf16.
// ---------------------------------------------------------------------------
__global__ __launch_bounds__(256) void k_gemm_lr(const u16* __restrict__ msaF,
                                                 const u16* __restrict__ WlrF,
                                                 const float* __restrict__ bl,
                                                 const float* __restrict__ br,
                                                 u16* __restrict__ leftT,
                                                 u16* __restrict__ rightT)
{
  int lane = threadIdx.x & 63, wid = threadIdx.x >> 6;
  int sIdx = blockIdx.x;
  f4v acc[4][4] = {};
  #pragma unroll
  for (int ks = 0; ks < 8; ++ks) {
    s8v a[4], bb[4];
    #pragma unroll
    for (int mi = 0; mi < 4; ++mi)
      a[mi] = *(const s8v*)(msaF + ((size_t)(sIdx * 16 + wid * 4 + mi) * 8 + ks) * 512 + lane * 8);
    #pragma unroll
    for (int ni = 0; ni < 4; ++ni)
      bb[ni] = *(const s8v*)(WlrF + ((size_t)(ni * 8 + ks)) * 512 + lane * 8);
    #pragma unroll
    for (int mi = 0; mi < 4; ++mi)
      #pragma unroll
      for (int ni = 0; ni < 4; ++ni)
        acc[mi][ni] = MFMA(a[mi], bb[ni], acc[mi][ni]);
  }
  #pragma unroll
  for (int mi = 0; mi < 4; ++mi) {
    #pragma unroll
    for (int ni = 0; ni < 4; ++ni) {
      int n = ni * 16 + (lane & 15);
      #pragma unroll
      for (int r = 0; r < 4; ++r) {
        int l = wid * 64 + mi * 16 + (lane >> 4) * 4 + r;
        float v = acc[mi][ni][r];
        if (n < 32) {
          leftT[((size_t)l * 32 + n) * 128 + sIdx] = f2bf(v + bl[n]);
        } else {
          rightT[((size_t)l * 32 + (n - 32)) * 128 + sIdx] =
              f2bf((v + br[n - 32]) * (1.f / NS));
        }
      }
    }
  }
}

// ---------------------------------------------------------------------------
// K3: fragpack -> leftF / rightF fragment tiles. grid 256.
// ---------------------------------------------------------------------------
__global__ __launch_bounds__(256) void k_fragpack(const u16* __restrict__ leftT,
                                                  const u16* __restrict__ rightT,
                                                  u16* __restrict__ leftF,
                                                  u16* __restrict__ rightF)
{
  __shared__ alignas(16) u16 lds[64 * 136];
  int t = threadIdx.x, bx = blockIdx.x;
  bool isR = bx >= 128;
  int blk = isR ? (bx - 128) : bx;
  #pragma unroll
  for (int it = 0; it < 4; ++it) {
    int u = it * 256 + t;
    int row = u >> 4, sc = u & 15;
    const u16* src;
    if (!isR) {
      src = leftT + ((size_t)(blk * 64 + row)) * 128 + sc * 8;
    } else {
      int gcol = blk * 64 + row;
      int mg = gcol >> 10, rem = gcol & 1023;
      int jc = rem >> 8, nc = rem & 255;
      int m = mg * 32 + (nc >> 3), j = jc * 8 + (nc & 7);
      src = rightT + ((size_t)(m * 32 + j)) * 128 + sc * 8;
    }
    *(s8v*)(lds + row * 136 + sc * 8) = *(const s8v*)src;
  }
  __syncthreads();
  u16* dst = (isR ? rightF : leftF) + (size_t)blk * 8192;
  #pragma unroll
  for (int it = 0; it < 4; ++it) {
    int o = it * 256 + t;
    int tloc = o >> 6, u = o & 63;
    int rb = tloc >> 2, sc2 = tloc & 3;
    int kslot = u >> 4, rr = u & 15;
    int row = rb * 16 + rr, s0 = sc2 * 32 + kslot * 8;
    *(s8v*)(dst + (size_t)o * 8) = *(const s8v*)(lds + row * 136 + s0);
  }
}

// ---------------------------------------------------------------------------
// K4: fused outer-product + Wo-proj + proj_down (R12 single-buffer + XCD).
// ---------------------------------------------------------------------------
__global__ __launch_bounds__(512, 4) void k_fused(
    const u16* __restrict__ leftF, const u16* __restrict__ rightF,
    const u16* __restrict__ WoF, const u16* __restrict__ pairF,
    const u16* __restrict__ WdF, const float* __restrict__ bo,
    const float* __restrict__ bd, u16* __restrict__ pN)
{
  __shared__ alignas(16) u16 Als[8192];    // 16 KB
  __shared__ alignas(16) u16 opL[16384];   // 32 KB
  __shared__ alignas(16) u16 obL[8192];    // 16 KB
  int t = threadIdx.x, lane = t & 63, w = t >> 6;
  int rlo = lane & 15, slot = lane >> 4;
  int b = blockIdx.x;
  int mg = b & 7, lp = b >> 3;             // XCD swizzle (1024 % 8 == 0)
  int l0 = lp * 2, m0 = mg * 32;

  #pragma unroll
  for (int i = 0; i < 2; ++i) {
    int u = t + 512 * i;
    *(s8v*)(Als + (size_t)u * 8) = *(const s8v*)(leftF + (size_t)lp * 8192 + (size_t)u * 8);
  }

  f4v acc2[4] = {};
  s8v bb[8];
  #pragma unroll
  for (int ks = 0; ks < 4; ++ks)
    #pragma unroll
    for (int ni = 0; ni < 2; ++ni)
      bb[ks * 2 + ni] = *(const s8v*)(rightF +
          ((size_t)((mg * 64 + 0 * 16 + w * 2 + ni) * 4 + ks)) * 512 + lane * 8);
  __syncthreads();

  #pragma unroll
  for (int jc = 0; jc < 4; ++jc) {
    f4v acc1[4][2] = {};
    __builtin_amdgcn_s_setprio(1);
    #pragma unroll
    for (int ks = 0; ks < 4; ++ks) {
      s8v a[4];
      #pragma unroll
      for (int mi = 0; mi < 4; ++mi)
        a[mi] = *(const s8v*)(Als + (size_t)(mi * 4 + ks) * 512 + lane * 8);
      #pragma unroll
      for (int mi = 0; mi < 4; ++mi)
        #pragma unroll
        for (int ni = 0; ni < 2; ++ni)
          acc1[mi][ni] = MFMA(a[mi], bb[ks * 2 + ni], acc1[mi][ni]);
    }
    __builtin_amdgcn_s_setprio(0);
    #pragma unroll
    for (int mi = 0; mi < 4; ++mi) {
      int i0 = (mi & 1) * 16 + slot * 4;
      int lLoc = mi >> 1;
      int kslot = (i0 >> 3) & 3;
      #pragma unroll
      for (int ni = 0; ni < 2; ++ni) {
        int n = w * 32 + ni * 16 + rlo;
        int pix = lLoc * 32 + (n >> 3);
        int jj = n & 7;
        uint2 o2;
        o2.x = cvtpk2(acc1[mi][ni][0], acc1[mi][ni][1]);
        o2.y = cvtpk2(acc1[mi][ni][2], acc1[mi][ni][3]);
        int byte = ((pix >> 4) * 8 + jj) * 1024 +
                   (kslot * 16 + ((pix & 15) ^ jj)) * 16 + (i0 & 7) * 2;
        *(uint2*)((char*)opL + byte) = o2;
      }
    }
    s8v wb[8];
    #pragma unroll
    for (int ks = 0; ks < 8; ++ks)
      wb[ks] = *(const s8v*)(WoF + ((size_t)(w * 32 + jc * 8 + ks)) * 512 + lane * 8);
    __syncthreads();
    __builtin_amdgcn_s_setprio(1);
    #pragma unroll
    for (int ks = 0; ks < 8; ++ks) {
      s8v a[4];
      #pragma unroll
      for (int mi = 0; mi < 4; ++mi) {
        int byte = (mi * 8 + ks) * 1024 + (slot * 16 + (rlo ^ ks)) * 16;
        a[mi] = *(const s8v*)((const char*)opL + byte);
      }
      #pragma unroll
      for (int mi = 0; mi < 4; ++mi)
        acc2[mi] = MFMA(a[mi], wb[ks], acc2[mi]);
    }
    __builtin_amdgcn_s_setprio(0);
    if (jc < 3) {
      #pragma unroll
      for (int ks = 0; ks < 4; ++ks)
        #pragma unroll
        for (int ni = 0; ni < 2; ++ni)
          bb[ks * 2 + ni] = *(const s8v*)(rightF +
              ((size_t)((mg * 64 + (jc + 1) * 16 + w * 2 + ni) * 4 + ks)) * 512 + lane * 8);
    }
    __syncthreads();
  }

  {
    int c = w * 16 + rlo;
    float bias = bo[c];
    #pragma unroll
    for (int mi = 0; mi < 4; ++mi)
      #pragma unroll
      for (int r = 0; r < 4; ++r) {
        int pix = mi * 16 + slot * 4 + r;
        int byte = (pix * 256 + c * 2) ^ ((pix & 7) << 4);
        *(u16*)((char*)obL + byte) = f2bf(acc2[mi][r] + bias);
      }
  }
  __syncthreads();

  int wr = w >> 2, wcq = w & 3;
  int pix0 = wr * 32, c0 = wcq * 32;
  {
    f4v acc[2][2] = {};
    #pragma unroll
    for (int ks = 0; ks < 4; ++ks) {        // K 0..127 from pairF
      s8v a[2], b2[2];
      #pragma unroll
      for (int mi = 0; mi < 2; ++mi) {
        int pb = (l0 + wr) * 16 + (m0 >> 4) + mi;
        a[mi] = *(const s8v*)(pairF + ((size_t)(pb * 4 + ks)) * 512 + lane * 8);
      }
      #pragma unroll
      for (int ni = 0; ni < 2; ++ni) {
        int cblk = wcq * 2 + ni;
        b2[ni] = *(const s8v*)(WdF + ((size_t)(cblk * 8 + ks)) * 512 + lane * 8);
      }
      #pragma unroll
      for (int mi = 0; mi < 2; ++mi)
        #pragma unroll
        for (int ni = 0; ni < 2; ++ni)
          acc[mi][ni] = MFMA(a[mi], b2[ni], acc[mi][ni]);
    }
    #pragma unroll
    for (int ks = 0; ks < 4; ++ks) {        // K 128..255 from obL
      s8v a[2], b2[2];
      #pragma unroll
      for (int mi = 0; mi < 2; ++mi) {
        int pix = pix0 + mi * 16 + rlo;
        int k = ks * 32 + slot * 8;
        int byte = (pix * 256 + k * 2) ^ ((pix & 7) << 4);
        a[mi] = *(const s8v*)((const char*)obL + byte);
      }
      #pragma unroll
      for (int ni = 0; ni < 2; ++ni) {
        int cblk = wcq * 2 + ni;
        b2[ni] = *(const s8v*)(WdF + ((size_t)(cblk * 8 + 4 + ks)) * 512 + lane * 8);
      }
      #pragma unroll
      for (int mi = 0; mi < 2; ++mi)
        #pragma unroll
        for (int ni = 0; ni < 2; ++ni)
          acc[mi][ni] = MFMA(a[mi], b2[ni], acc[mi][ni]);
    }
    #pragma unroll
    for (int mi = 0; mi < 2; ++mi)
      #pragma unroll
      for (int ni = 0; ni < 2; ++ni) {
        int c = c0 + ni * 16 + rlo;
        float bias = bd[c];
        #pragma unroll
        for (int r = 0; r < 4; ++r) {
          int pix = pix0 + mi * 16 + slot * 4 + r;
          int byte = (pix * 256 + c * 2) ^ ((pix & 7) << 4);
          *(u16*)((char*)opL + byte) = f2bf(acc[mi][ni][r] + bias);
        }
      }
  }
  __syncthreads();

  #pragma unroll
  for (int q = 0; q < 2; ++q) {
    int u = q * 512 + t;
    int pix = u >> 4, off = u & 15;
    int byte = (pix * 256 + off * 16) ^ ((pix & 7) << 4);
    uint4 v = *(const uint4*)((const char*)opL + byte);
    int pixG = (l0 + (pix >> 5)) * 256 + m0 + (pix & 31);
    *(uint4*)(pN + (size_t)pixG * 128 + off * 8) = v;
  }
}

// ---------------------------------------------------------------------------
// K5: conv3x3 implicit-GEMM MFMA + XCD swizzle. FUSE_IN variant also reduces
// conv1's IN partials into folded (sc,b2) in LDS. grid 512.
// ---------------------------------------------------------------------------
#define CLOADB(s, B) {                                                        \
    _Pragma("unroll")                                                         \
    for (int j = 0; j < 2; ++j) {                                             \
      const int st_ = (s) + j;                                                \
      _Pragma("unroll")                                                       \
      for (int ni = 0; ni < 4; ++ni) {                                        \
        int co_ = co0 + ni * 16 + rlo;                                        \
        B[j][ni] = *(const s8v*)(wP +                                         \
            ((size_t)(st_ * 128 + co_) * 4 + slot) * 8);                      \
      }                                                                       \
    } }
#define CSTEP2(s, B) {                                                        \
    _Pragma("unroll")                                                         \
    for (int j = 0; j < 2; ++j) {                                             \
      const int st_ = (s) + j, tap_ = st_ >> 2, kk_ = st_ & 3;                \
      const int dy_ = tap_ / 3, dx_ = tap_ % 3;                               \
      s8v a_[4];                                                              \
      _Pragma("unroll")                                                       \
      for (int mi = 0; mi < 4; ++mi) {                                        \
        int p_ = mi * 16 + rlo + dx_;                                         \
        int lb_ = (((wpy + dy_) * 66 + p_) * 256 + kk_ * 64 + slot * 16) ^    \
                  ((p_ & 7) << 4);                                            \
        a_[mi] = *(const s8v*)((const char*)Ast + lb_);                       \
      }                                                                       \
      __builtin_amdgcn_s_setprio(1);                                          \
      _Pragma("unroll")                                                       \
      for (int mi = 0; mi < 4; ++mi)                                          \
        _Pragma("unroll")                                                     \
        for (int ni = 0; ni < 4; ++ni)                                        \
          acc[mi][ni] = MFMA(a_[mi], B[j][ni], acc[mi][ni]);                  \
      __builtin_amdgcn_s_setprio(0);                                          \
    } }

template<bool FUSE_IN>
__global__ __launch_bounds__(256, 2) void k_conv(const u16* __restrict__ inN,
                                                 const float* __restrict__ gSin,
                                                 const float* __restrict__ gQin,
                                                 const float* __restrict__ ing,
                                                 const float* __restrict__ inb,
                                                 const u16* __restrict__ wP,
                                                 u16* __restrict__ outB,
                                                 float* __restrict__ gSout,
                                                 float* __restrict__ gQout)
{
  __shared__ alignas(16) u16 Ast[4 * 66 * 128];   // 67584 B (reused as f32 out)
  __shared__ float partS[4][64], partQ[4][64];
  __shared__ alignas(16) float sstat[256];
  __shared__ float red2[4][128];
  int t = threadIdx.x, lane = t & 63, w = t >> 6;
  int rlo = lane & 15, slot = lane >> 4;
  int b = blockIdx.x;
  int L = (b & 7) * 64 + (b >> 3);               // XCD swizzle (512 % 8 == 0)
  int xt = L & 3, yt = L >> 2;
  int x0 = xt * 64, y0 = yt * 2;

  if constexpr (FUSE_IN) {
    int c = t & 127, h = t >> 7;
    float s = 0.f, q = 0.f;
    for (int i = h * 256; i < h * 256 + 256; ++i) {
      s += gSin[i * 128 + c];
      q += gQin[i * 128 + c];
    }
    red2[h][c] = s; red2[2 + h][c] = q;
    __syncthreads();
    if (t < 128) {
      float ss = red2[0][t] + red2[1][t];
      float qq = red2[2][t] + red2[3][t];
      float m = ss * (1.f / HW);
      float var = qq * (1.f / HW) - m * m;
      float rstd = rsqrtf(var + 1e-6f);
      float sc = rstd * ing[t];
      sstat[t] = sc;
      sstat[128 + t] = inb[t] - m * sc;
    }
    __syncthreads();
  }

  for (int u = t; u < 4224; u += 256) {
    int r = u / 1056;
    int rem = u - r * 1056;
    int p = rem >> 4, ku = rem & 15;
    int gy = y0 + r - 1, gx = x0 - 1 + p;
    s8v v = zero8();
    if ((unsigned)gy < 256u && (unsigned)gx < 256u) {
      v = *(const s8v*)(inN + ((size_t)gy * LL + gx) * 128 + ku * 8);
      if constexpr (FUSE_IN) {
        float4 s0 = ((const float4*)sstat)[ku * 2];
        float4 s1 = ((const float4*)sstat)[ku * 2 + 1];
        float4 q0 = ((const float4*)(sstat + 128))[ku * 2];
        float4 q1 = ((const float4*)(sstat + 128))[ku * 2 + 1];
        float f0 = elu1(bf2f((u16)v[0]) * s0.x + q0.x);
        float f1 = elu1(bf2f((u16)v[1]) * s0.y + q0.y);
        float f2 = elu1(bf2f((u16)v[2]) * s0.z + q0.z);
        float f3 = elu1(bf2f((u16)v[3]) * s0.w + q0.w);
        float f4 = elu1(bf2f((u16)v[4]) * s1.x + q1.x);
        float f5 = elu1(bf2f((u16)v[5]) * s1.y + q1.y);
        float f6 = elu1(bf2f((u16)v[6]) * s1.z + q1.z);
        float f7 = elu1(bf2f((u16)v[7]) * s1.w + q1.w);
        uint4 uv;
        uv.x = cvtpk2(f0, f1); uv.y = cvtpk2(f2, f3);
        uv.z = cvtpk2(f4, f5); uv.w = cvtpk2(f6, f7);
        v = __builtin_bit_cast(s8v, uv);
      }
    }
    int lb = (u * 16) ^ ((p & 7) << 4);
    *(s8v*)((char*)Ast + lb) = v;
  }
  __syncthreads();
  int wpy = w >> 1, co0 = (w & 1) * 64;
  f4v acc[4][4] = {};
  s8v bA[2][4], bB[2][4];
  CLOADB(0, bA)
  #pragma unroll
  for (int s = 0; s < 36; s += 4) {
    CLOADB(s + 2, bB)
    CSTEP2(s, bA)
    if (s + 4 < 36) { CLOADB(s + 4, bA) }
    CSTEP2(s + 2, bB)
  }
  // IN partial stats from registers
  #pragma unroll
  for (int ni = 0; ni < 4; ++ni) {
    float s = 0.f, q = 0.f;
    #pragma unroll
    for (int mi = 0; mi < 4; ++mi)
      #pragma unroll
      for (int r = 0; r < 4; ++r) {
        float v = acc[mi][ni][r];
        s += v; q += v * v;
      }
    s += __shfl_xor(s, 16); s += __shfl_xor(s, 32);
    q += __shfl_xor(q, 16); q += __shfl_xor(q, 32);
    if (slot == 0) { partS[w][ni * 16 + rlo] = s; partQ[w][ni * 16 + rlo] = q; }
  }
  __syncthreads();           // all Ast reads done; safe to reuse
  float* AstF = (float*)Ast; // [wpy][64 px][128 co] f32, XOR (pix&7)<<4
  #pragma unroll
  for (int mi = 0; mi < 4; ++mi)
    #pragma unroll
    for (int ni = 0; ni < 4; ++ni) {
      int co = co0 + ni * 16 + rlo;
      #pragma unroll
      for (int r = 0; r < 4; ++r) {
        int pix = mi * 16 + slot * 4 + r;
        int byte = wpy * 32768 + ((pix * 512 + co * 4) ^ ((pix & 7) << 4));
        *(float*)((char*)AstF + byte) = acc[mi][ni][r];
      }
    }
  if (t < 128) {
    int half = t >> 6, cl = t & 63;
    gSout[b * 128 + t] = partS[half][cl] + partS[2 + half][cl];
    gQout[b * 128 + t] = partQ[half][cl] + partQ[2 + half][cl];
  }
  __syncthreads();
  #pragma unroll
  for (int it = 0; it < 8; ++it) {
    int u = it * 256 + t;                   // 2048 units of 8 channels
    int wpy2 = u >> 10, rem = u & 1023;
    int pix = rem >> 4, cv8 = rem & 15;
    int base = wpy2 * 32768;
    int b0b = base + ((pix * 512 + cv8 * 32) ^ ((pix & 7) << 4));
    int b1b = base + ((pix * 512 + cv8 * 32 + 16) ^ ((pix & 7) << 4));
    float4 a = *(const float4*)((const char*)AstF + b0b);
    float4 bv = *(const float4*)((const char*)AstF + b1b);
    uint4 o;
    o.x = cvtpk2(a.x, a.y); o.y = cvtpk2(a.z, a.w);
    o.z = cvtpk2(bv.x, bv.y); o.w = cvtpk2(bv.z, bv.w);
    *(uint4*)(outB + ((size_t)(y0 + wpy2) * LL + x0 + pix) * 128 + cv8 * 8) = o;
  }
}

// ---------------------------------------------------------------------------
// K6: PARALLEL stats reduce: one block per channel (grid 128, block 512).
// Each thread loads exactly one partial pair; wave shuffle-reduce + LDS tree.
// ---------------------------------------------------------------------------
__global__ __launch_bounds__(512) void k_instat2(const float* __restrict__ gS,
                                                 const float* __restrict__ gQ,
                                                 const float* __restrict__ g,
                                                 const float* __restrict__ b,
                                                 float* __restrict__ st)
{
  __shared__ float redS[8], redQ[8];
  int c = blockIdx.x, t = threadIdx.x;
  int lane = t & 63, w = t >> 6;
  float s = gS[(size_t)t * 128 + c];
  float q = gQ[(size_t)t * 128 + c];
  #pragma unroll
  for (int off = 32; off; off >>= 1) {
    s += __shfl_down(s, off);
    q += __shfl_down(q, off);
  }
  if (lane == 0) { redS[w] = s; redQ[w] = q; }
  __syncthreads();
  if (t == 0) {
    float ss = 0.f, qq = 0.f;
    #pragma unroll
    for (int i = 0; i < 8; ++i) { ss += redS[i]; qq += redQ[i]; }
    float m = ss * (1.f / HW);
    float var = qq * (1.f / HW) - m * m;
    float rstd = rsqrtf(var + 1e-6f);
    float sc = rstd * g[c];
    st[c] = sc;
    st[128 + c] = b[c] - m * sc;
  }
}

// ---------------------------------------------------------------------------
// K7: out = elu(pN + IN2(h2raw)); 8-ch units. grid 4096.
// ---------------------------------------------------------------------------
__global__ __launch_bounds__(256) void k_final(const u16* __restrict__ pN,
                                               const u16* __restrict__ h2,
                                               const float* __restrict__ st,
                                               float* __restrict__ out)
{
  int i = blockIdx.x * 256 + threadIdx.x;   // 1,048,576 uint4 units
  int c8 = i & 15;
  uint4 hv = ((const uint4*)h2)[i];
  uint4 pv = ((const uint4*)pN)[i];
  float4 s0 = ((const float4*)st)[c8 * 2], s1 = ((const float4*)st)[c8 * 2 + 1];
  float4 q0 = ((const float4*)(st + 128))[c8 * 2], q1 = ((const float4*)(st + 128))[c8 * 2 + 1];
  float4 f0, f1;
  f0.x = bf2f((u16)(hv.x & 0xffff)) * s0.x + q0.x + bf2f((u16)(pv.x & 0xffff));
  f0.y = bf2f((u16)(hv.x >> 16))    * s0.y + q0.y + bf2f((u16)(pv.x >> 16));
  f0.z = bf2f((u16)(hv.y & 0xffff)) * s0.z + q0.z + bf2f((u16)(pv.y & 0xffff));
  f0.w = bf2f((u16)(hv.y >> 16))    * s0.w + q0.w + bf2f((u16)(pv.y >> 16));
  f1.x = bf2f((u16)(hv.z & 0xffff)) * s1.x + q1.x + bf2f((u16)(pv.z & 0xffff));
  f1.y = bf2f((u16)(hv.z >> 16))    * s1.y + q1.y + bf2f((u16)(pv.z >> 16));
  f1.z = bf2f((u16)(hv.w & 0xffff)) * s1.z + q1.z + bf2f((u16)(pv.w & 0xffff));
  f1.w = bf2f((u16)(hv.w >> 16))    * s1.w + q1.w + bf2f((u16)(pv.w >> 16));
  f0.x = elu1(f0.x); f0.y = elu1(f0.y); f0.z = elu1(f0.z); f0.w = elu1(f0.w);
  f1.x = elu1(f1.x); f1.y = elu1(f1.y); f1.z = elu1(f1.z); f1.w = elu1(f1.w);
  ((float4*)out)[(size_t)i * 2]     = f0;
  ((float4*)out)[(size_t)i * 2 + 1] = f1;
}

// ---------------------------------------------------------------------------
extern "C" void kernel_launch(void* const* d_in, const int* in_sizes, int n_in,
                              void* d_out, int out_size, void* d_ws, size_t ws_size,
                              hipStream_t stream)
{
  const float* msa   = (const float*)d_in[0];
  const float* pair  = (const float*)d_in[1];
  const float* ln_g  = (const float*)d_in[2];
  const float* ln_b  = (const float*)d_in[3];
  const float* Wl    = (const float*)d_in[4];
  const float* bl    = (const float*)d_in[5];
  const float* Wr    = (const float*)d_in[6];
  const float* br    = (const float*)d_in[7];
  const float* Wo    = (const float*)d_in[8];
  const float* bo    = (const float*)d_in[9];
  const float* Wd    = (const float*)d_in[10];
  const float* bd    = (const float*)d_in[11];
  const float* conv1 = (const float*)d_in[12];
  const float* in1_g = (const float*)d_in[13];
  const float* in1_b = (const float*)d_in[14];
  const float* conv2 = (const float*)d_in[15];
  const float* in2_g = (const float*)d_in[16];
  const float* in2_b = (const float*)d_in[17];
  float* out = (float*)d_out;

  // Workspace (F = 1Mi floats = 4 MB), peak ~86 MB.
  float* ws = (float*)d_ws;
  const size_t F = 1048576;
  u16* msaF   = (u16*)ws;
  u16* leftT  = (u16*)(ws + 4 * F);
  u16* rightT = (u16*)(ws + 4 * F + F / 2);
  u16* leftF  = (u16*)(ws + 5 * F);
  u16* rightF = (u16*)(ws + 5 * F + F / 2);
  u16* pN     = (u16*)(ws + 6 * F);
  u16* h1raw  = (u16*)(ws + 10 * F);
  u16* h2raw  = (u16*)(ws + 14 * F);
  u16* pairF  = (u16*)(ws + 18 * F);
  float* gS1  = ws + 22 * F;                 // 65536
  float* gQ1  = ws + 22 * F + 65536;
  float* gS2  = ws + 22 * F + 131072;
  float* gQ2  = ws + 22 * F + 196608;
  float* stats = ws + 22 * F + 262144;       // 256
  u16* aux    = (u16*)(ws + 22 * F + 262400);
  u16* wP1    = aux;                         // 147456
  u16* wP2    = aux + 147456;                // 147456
  u16* WoF    = aux + 294912;                // 131072
  u16* WdF    = aux + 425984;                // 32768
  u16* WlrF   = aux + 458752;                // 16384

  k_prep_ln<<<dim3(6376), dim3(256), 0, stream>>>(Wl, Wr, Wo, Wd, conv1, conv2,
                                                  pair, msa, ln_g, ln_b,
                                                  WlrF, WoF, WdF, wP1, wP2, pairF, msaF);
  k_gemm_lr<<<dim3(128), dim3(256), 0, stream>>>(msaF, WlrF, bl, br, leftT, rightT);
  k_fragpack<<<dim3(256), dim3(256), 0, stream>>>(leftT, rightT, leftF, rightF);

  k_fused<<<dim3(1024), dim3(512), 0, stream>>>(leftF, rightF, WoF, pairF, WdF,
                                                bo, bd, pN);

  k_conv<false><<<dim3(512), dim3(256), 0, stream>>>(pN, nullptr, nullptr,
                                                     nullptr, nullptr,
                                                     wP1, h1raw, gS1, gQ1);
  k_conv<true><<<dim3(512), dim3(256), 0, stream>>>(h1raw, gS1, gQ1, in1_g, in1_b,
                                                    wP2, h2raw, gS2, gQ2);
  k_instat2<<<dim3(128), dim3(512), 0, stream>>>(gS2, gQ2, in2_g, in2_b, stats);

  k_final<<<dim3(4096), dim3(256), 0, stream>>>(pN, h2raw, stats, out);
}

// Round 21
// 174.003 us; speedup vs baseline: 2.5639x; 1.0312x over previous
//
#include <hip/hip_runtime.h>
#include <math.h>

#define LL 256      // L
#define NS 128      // N sequences
#define DM 256      // d_msa
#define DH 32       // d_h
#define DP 128      // d_pair
#define HW 65536    // L*L

using u16 = unsigned short;
typedef __attribute__((ext_vector_type(8))) short s8v;   // 8 bf16 (A/B frag)
typedef __attribute__((ext_vector_type(4))) short s4v;   // 4 bf16
typedef __attribute__((ext_vector_type(4))) float f4v;   // C/D frag

#define MFMA(a, b, c) __builtin_amdgcn_mfma_f32_16x16x32_bf16((a), (b), (c), 0, 0, 0)

__device__ __forceinline__ u16 f2bf(float f) {
  unsigned u = __float_as_uint(f);
  u = (u + 0x7FFFu + ((u >> 16) & 1u)) >> 16;   // RNE
  return (u16)u;
}
__device__ __forceinline__ unsigned cvtpk2(float lo, float hi) {
  unsigned r;
  asm("v_cvt_pk_bf16_f32 %0, %1, %2" : "=v"(r) : "v"(lo), "v"(hi));
  return r;
}
__device__ __forceinline__ float bf2f(u16 h) { return __uint_as_float(((unsigned)h) << 16); }
__device__ __forceinline__ float elu1(float v) { return v > 0.f ? v : expm1f(v); }
__device__ __forceinline__ s8v zero8() {
  s8v v;
  #pragma unroll
  for (int j = 0; j < 8; ++j) v[j] = 0;
  return v;
}

// Fragment-tile layout: 1 KB tile = 16 rows x 32 k (bf16).
// unit(16B) = ((k>>3)&3)*16 + (row&15) ; elem = k&7.
// Wave fragment load = tile_base + lane*16 (fully coalesced).

// ---------------------------------------------------------------------------
// P: weight preps (fragment-tiled) + pairF + LayerNorm->msaF, one launch.
// ---------------------------------------------------------------------------
__device__ __forceinline__ void prep_convw(const float* __restrict__ w,
                                           u16* __restrict__ wP, int idx)
{
  int h = idx & 3, co = (idx >> 2) & 127, kk = (idx >> 9) & 3, tap = idx >> 11;
  s8v o;
  #pragma unroll
  for (int j = 0; j < 8; ++j) {
    int ci = kk * 32 + h * 8 + j;
    o[j] = (short)f2bf(w[((size_t)co * DP + ci) * 9 + tap]);
  }
  *(s8v*)(wP + (size_t)idx * 8) = o;
}

__global__ __launch_bounds__(256) void k_prep_ln(
    const float* __restrict__ Wl, const float* __restrict__ Wr,
    const float* __restrict__ Wo, const float* __restrict__ Wd,
    const float* __restrict__ conv1, const float* __restrict__ conv2,
    const float* __restrict__ pair,
    const float* __restrict__ msa, const float* __restrict__ ln_g,
    const float* __restrict__ ln_b,
    u16* __restrict__ WlrF, u16* __restrict__ WoF, u16* __restrict__ WdF,
    u16* __restrict__ wP1, u16* __restrict__ wP2, u16* __restrict__ pairF,
    u16* __restrict__ msaF)
{
  __shared__ alignas(16) u16 buf[16 * 264];
  int bx = blockIdx.x, t = threadIdx.x;
  if (bx < 64) {
    int o = bx * 256 + t;
    int tile = o >> 6, u = o & 63;
    int cblk = tile >> 5, j = tile & 31;
    int kslot = u >> 4, cl = u & 15;
    int c = cblk * 16 + cl;
    s8v v;
    #pragma unroll
    for (int e = 0; e < 8; ++e) {
      int i = kslot * 8 + e;
      v[e] = (short)f2bf(Wo[(size_t)(i * 32 + j) * DP + c]);
    }
    *(s8v*)(WoF + (size_t)o * 8) = v;
  } else if (bx < 80) {
    int o = (bx - 64) * 256 + t;
    int tile = o >> 6, u = o & 63;
    int cblk = tile >> 3, kch = tile & 7;
    int kslot = u >> 4, cl = u & 15;
    int c = cblk * 16 + cl;
    s8v v;
    #pragma unroll
    for (int e = 0; e < 8; ++e) {
      int k = kch * 32 + kslot * 8 + e;
      v[e] = (short)f2bf(Wd[(size_t)k * DP + c]);
    }
    *(s8v*)(WdF + (size_t)o * 8) = v;
  } else if (bx < 88) {
    int o = (bx - 80) * 256 + t;
    int tile = o >> 6, u = o & 63;
    int nblk = tile >> 3, kch = tile & 7;
    int kslot = u >> 4, cl = u & 15;
    int n = nblk * 16 + cl;
    s8v v;
    #pragma unroll
    for (int e = 0; e < 8; ++e) {
      int k = kch * 32 + kslot * 8 + e;
      float x = (n < 32) ? Wl[k * DH + n] : Wr[k * DH + (n - 32)];
      v[e] = (short)f2bf(x);
    }
    *(s8v*)(WlrF + (size_t)o * 8) = v;
  } else if (bx < 160) {
    prep_convw(conv1, wP1, (bx - 88) * 256 + t);
  } else if (bx < 232) {
    prep_convw(conv2, wP2, (bx - 160) * 256 + t);
  } else if (bx < 4328) {
    int pb = bx - 232;
    #pragma unroll
    for (int it = 0; it < 2; ++it) {
      int idx = it * 256 + t;
      int pix = idx >> 5, f4i = idx & 31;
      float4 v = ((const float4*)pair)[(size_t)(pb * 16 + pix) * 32 + f4i];
      s4v o;
      o[0] = (short)f2bf(v.x); o[1] = (short)f2bf(v.y);
      o[2] = (short)f2bf(v.z); o[3] = (short)f2bf(v.w);
      *(s4v*)(buf + pix * 136 + f4i * 4) = o;
    }
    __syncthreads();
    int kch = t >> 6, u = t & 63;
    int kslot = u >> 4, cl = u & 15;
    int k0 = kch * 32 + kslot * 8;
    s8v v = *(const s8v*)(buf + cl * 136 + k0);
    *(s8v*)(pairF + ((size_t)pb * 256 + t) * 8) = v;
  } else {
    int bid = bx - 4328;
    int lane = t & 63, wid = t >> 6;
    int row0 = bid * 16;
    const float4 gv = ((const float4*)ln_g)[lane];
    const float4 bv = ((const float4*)ln_b)[lane];
    #pragma unroll
    for (int rr = 0; rr < 4; ++rr) {
      int row = row0 + wid * 4 + rr;
      float4 v = ((const float4*)(msa + (size_t)row * DM))[lane];
      float s = v.x + v.y + v.z + v.w;
      float q = v.x * v.x + v.y * v.y + v.z * v.z + v.w * v.w;
      #pragma unroll
      for (int off = 32; off; off >>= 1) { s += __shfl_down(s, off); q += __shfl_down(q, off); }
      s = __shfl(s, 0); q = __shfl(q, 0);
      float mean = s * (1.f / DM);
      float var  = q * (1.f / DM) - mean * mean;
      float rstd = rsqrtf(var + 1e-5f);
      s4v o;
      o[0] = (short)f2bf((v.x - mean) * rstd * gv.x + bv.x);
      o[1] = (short)f2bf((v.y - mean) * rstd * gv.y + bv.y);
      o[2] = (short)f2bf((v.z - mean) * rstd * gv.z + bv.z);
      o[3] = (short)f2bf((v.w - mean) * rstd * gv.w + bv.w);
      *(s4v*)(buf + (wid * 4 + rr) * 264 + lane * 4) = o;
    }
    __syncthreads();
    #pragma unroll
    for (int it = 0; it < 2; ++it) {
      int o = it * 256 + t;
      int kch = o >> 6, kslot = (o >> 4) & 3, rr = o & 15;
      int k0 = kch * 32 + kslot * 8;
      s8v v = *(const s8v*)(buf + rr * 264 + k0);
      *(s8v*)(msaF + (size_t)bid * 4096 + (size_t)o * 8) = v;
    }
  }
}

// ---------------------------------------------------------------------------
// K2: msaF @ WlrF -> leftT/rightT bf16. grid 256 (s = bx>>1, row-half =
// bx&1): full-CU coverage vs the old grid-128 (half the GPU idle).
// ---------------------------------------------------------------------------
__global__ __launch_bounds__(256) void k_gemm_lr(const u16* __restrict__ msaF,
                                                 const u16* __restrict__ WlrF,
                                                 const float* __restrict__ bl,
                                                 const float* __restrict__ br,
                                                 u16* __restrict__ leftT,
                                                 u16* __restrict__ rightT)
{
  int lane = threadIdx.x & 63, wid = threadIdx.x >> 6;
  int sIdx = blockIdx.x >> 1, half = blockIdx.x & 1;
  f4v acc[2][4] = {};
  #pragma unroll
  for (int ks = 0; ks < 8; ++ks) {
    s8v a[2], bb[4];
    #pragma unroll
    for (int mi = 0; mi < 2; ++mi)
      a[mi] = *(const s8v*)(msaF +
          ((size_t)(sIdx * 16 + half * 8 + wid * 2 + mi) * 8 + ks) * 512 + lane * 8);
    #pragma unroll
    for (int ni = 0; ni < 4; ++ni)
      bb[ni] = *(const s8v*)(WlrF + ((size_t)(ni * 8 + ks)) * 512 + lane * 8);
    #pragma unroll
    for (int mi = 0; mi < 2; ++mi)
      #pragma unroll
      for (int ni = 0; ni < 4; ++ni)
        acc[mi][ni] = MFMA(a[mi], bb[ni], acc[mi][ni]);
  }
  #pragma unroll
  for (int mi = 0; mi < 2; ++mi) {
    #pragma unroll
    for (int ni = 0; ni < 4; ++ni) {
      int n = ni * 16 + (lane & 15);
      #pragma unroll
      for (int r = 0; r < 4; ++r) {
        int l = half * 128 + (wid * 2 + mi) * 16 + (lane >> 4) * 4 + r;
        float v = acc[mi][ni][r];
        if (n < 32) {
          leftT[((size_t)l * 32 + n) * 128 + sIdx] = f2bf(v + bl[n]);
        } else {
          rightT[((size_t)l * 32 + (n - 32)) * 128 + sIdx] =
              f2bf((v + br[n - 32]) * (1.f / NS));
        }
      }
    }
  }
}

// ---------------------------------------------------------------------------
// K3: fragpack -> leftF / rightF fragment tiles. grid 256.
// ---------------------------------------------------------------------------
__global__ __launch_bounds__(256) void k_fragpack(const u16* __restrict__ leftT,
                                                  const u16* __restrict__ rightT,
                                                  u16* __restrict__ leftF,
                                                  u16* __restrict__ rightF)
{
  __shared__ alignas(16) u16 lds[64 * 136];
  int t = threadIdx.x, bx = blockIdx.x;
  bool isR = bx >= 128;
  int blk = isR ? (bx - 128) : bx;
  #pragma unroll
  for (int it = 0; it < 4; ++it) {
    int u = it * 256 + t;
    int row = u >> 4, sc = u & 15;
    const u16* src;
    if (!isR) {
      src = leftT + ((size_t)(blk * 64 + row)) * 128 + sc * 8;
    } else {
      int gcol = blk * 64 + row;
      int mg = gcol >> 10, rem = gcol & 1023;
      int jc = rem >> 8, nc = rem & 255;
      int m = mg * 32 + (nc >> 3), j = jc * 8 + (nc & 7);
      src = rightT + ((size_t)(m * 32 + j)) * 128 + sc * 8;
    }
    *(s8v*)(lds + row * 136 + sc * 8) = *(const s8v*)src;
  }
  __syncthreads();
  u16* dst = (isR ? rightF : leftF) + (size_t)blk * 8192;
  #pragma unroll
  for (int it = 0; it < 4; ++it) {
    int o = it * 256 + t;
    int tloc = o >> 6, u = o & 63;
    int rb = tloc >> 2, sc2 = tloc & 3;
    int kslot = u >> 4, rr = u & 15;
    int row = rb * 16 + rr, s0 = sc2 * 32 + kslot * 8;
    *(s8v*)(dst + (size_t)o * 8) = *(const s8v*)(lds + row * 136 + s0);
  }
}

// ---------------------------------------------------------------------------
// K4: fused outer-product + Wo-proj + proj_down (R12 single-buffer + XCD).
// ---------------------------------------------------------------------------
__global__ __launch_bounds__(512, 4) void k_fused(
    const u16* __restrict__ leftF, const u16* __restrict__ rightF,
    const u16* __restrict__ WoF, const u16* __restrict__ pairF,
    const u16* __restrict__ WdF, const float* __restrict__ bo,
    const float* __restrict__ bd, u16* __restrict__ pN)
{
  __shared__ alignas(16) u16 Als[8192];    // 16 KB
  __shared__ alignas(16) u16 opL[16384];   // 32 KB
  __shared__ alignas(16) u16 obL[8192];    // 16 KB
  int t = threadIdx.x, lane = t & 63, w = t >> 6;
  int rlo = lane & 15, slot = lane >> 4;
  int b = blockIdx.x;
  int mg = b & 7, lp = b >> 3;             // XCD swizzle (1024 % 8 == 0)
  int l0 = lp * 2, m0 = mg * 32;

  #pragma unroll
  for (int i = 0; i < 2; ++i) {
    int u = t + 512 * i;
    *(s8v*)(Als + (size_t)u * 8) = *(const s8v*)(leftF + (size_t)lp * 8192 + (size_t)u * 8);
  }

  f4v acc2[4] = {};
  s8v bb[8];
  #pragma unroll
  for (int ks = 0; ks < 4; ++ks)
    #pragma unroll
    for (int ni = 0; ni < 2; ++ni)
      bb[ks * 2 + ni] = *(const s8v*)(rightF +
          ((size_t)((mg * 64 + 0 * 16 + w * 2 + ni) * 4 + ks)) * 512 + lane * 8);
  __syncthreads();

  #pragma unroll
  for (int jc = 0; jc < 4; ++jc) {
    f4v acc1[4][2] = {};
    __builtin_amdgcn_s_setprio(1);
    #pragma unroll
    for (int ks = 0; ks < 4; ++ks) {
      s8v a[4];
      #pragma unroll
      for (int mi = 0; mi < 4; ++mi)
        a[mi] = *(const s8v*)(Als + (size_t)(mi * 4 + ks) * 512 + lane * 8);
      #pragma unroll
      for (int mi = 0; mi < 4; ++mi)
        #pragma unroll
        for (int ni = 0; ni < 2; ++ni)
          acc1[mi][ni] = MFMA(a[mi], bb[ks * 2 + ni], acc1[mi][ni]);
    }
    __builtin_amdgcn_s_setprio(0);
    #pragma unroll
    for (int mi = 0; mi < 4; ++mi) {
      int i0 = (mi & 1) * 16 + slot * 4;
      int lLoc = mi >> 1;
      int kslot = (i0 >> 3) & 3;
      #pragma unroll
      for (int ni = 0; ni < 2; ++ni) {
        int n = w * 32 + ni * 16 + rlo;
        int pix = lLoc * 32 + (n >> 3);
        int jj = n & 7;
        uint2 o2;
        o2.x = cvtpk2(acc1[mi][ni][0], acc1[mi][ni][1]);
        o2.y = cvtpk2(acc1[mi][ni][2], acc1[mi][ni][3]);
        int byte = ((pix >> 4) * 8 + jj) * 1024 +
                   (kslot * 16 + ((pix & 15) ^ jj)) * 16 + (i0 & 7) * 2;
        *(uint2*)((char*)opL + byte) = o2;
      }
    }
    s8v wb[8];
    #pragma unroll
    for (int ks = 0; ks < 8; ++ks)
      wb[ks] = *(const s8v*)(WoF + ((size_t)(w * 32 + jc * 8 + ks)) * 512 + lane * 8);
    __syncthreads();
    __builtin_amdgcn_s_setprio(1);
    #pragma unroll
    for (int ks = 0; ks < 8; ++ks) {
      s8v a[4];
      #pragma unroll
      for (int mi = 0; mi < 4; ++mi) {
        int byte = (mi * 8 + ks) * 1024 + (slot * 16 + (rlo ^ ks)) * 16;
        a[mi] = *(const s8v*)((const char*)opL + byte);
      }
      #pragma unroll
      for (int mi = 0; mi < 4; ++mi)
        acc2[mi] = MFMA(a[mi], wb[ks], acc2[mi]);
    }
    __builtin_amdgcn_s_setprio(0);
    if (jc < 3) {
      #pragma unroll
      for (int ks = 0; ks < 4; ++ks)
        #pragma unroll
        for (int ni = 0; ni < 2; ++ni)
          bb[ks * 2 + ni] = *(const s8v*)(rightF +
              ((size_t)((mg * 64 + (jc + 1) * 16 + w * 2 + ni) * 4 + ks)) * 512 + lane * 8);
    }
    __syncthreads();
  }

  {
    int c = w * 16 + rlo;
    float bias = bo[c];
    #pragma unroll
    for (int mi = 0; mi < 4; ++mi)
      #pragma unroll
      for (int r = 0; r < 4; ++r) {
        int pix = mi * 16 + slot * 4 + r;
        int byte = (pix * 256 + c * 2) ^ ((pix & 7) << 4);
        *(u16*)((char*)obL + byte) = f2bf(acc2[mi][r] + bias);
      }
  }
  __syncthreads();

  int wr = w >> 2, wcq = w & 3;
  int pix0 = wr * 32, c0 = wcq * 32;
  {
    f4v acc[2][2] = {};
    #pragma unroll
    for (int ks = 0; ks < 4; ++ks) {        // K 0..127 from pairF
      s8v a[2], b2[2];
      #pragma unroll
      for (int mi = 0; mi < 2; ++mi) {
        int pb = (l0 + wr) * 16 + (m0 >> 4) + mi;
        a[mi] = *(const s8v*)(pairF + ((size_t)(pb * 4 + ks)) * 512 + lane * 8);
      }
      #pragma unroll
      for (int ni = 0; ni < 2; ++ni) {
        int cblk = wcq * 2 + ni;
        b2[ni] = *(const s8v*)(WdF + ((size_t)(cblk * 8 + ks)) * 512 + lane * 8);
      }
      #pragma unroll
      for (int mi = 0; mi < 2; ++mi)
        #pragma unroll
        for (int ni = 0; ni < 2; ++ni)
          acc[mi][ni] = MFMA(a[mi], b2[ni], acc[mi][ni]);
    }
    #pragma unroll
    for (int ks = 0; ks < 4; ++ks) {        // K 128..255 from obL
      s8v a[2], b2[2];
      #pragma unroll
      for (int mi = 0; mi < 2; ++mi) {
        int pix = pix0 + mi * 16 + rlo;
        int k = ks * 32 + slot * 8;
        int byte = (pix * 256 + k * 2) ^ ((pix & 7) << 4);
        a[mi] = *(const s8v*)((const char*)obL + byte);
      }
      #pragma unroll
      for (int ni = 0; ni < 2; ++ni) {
        int cblk = wcq * 2 + ni;
        b2[ni] = *(const s8v*)(WdF + ((size_t)(cblk * 8 + 4 + ks)) * 512 + lane * 8);
      }
      #pragma unroll
      for (int mi = 0; mi < 2; ++mi)
        #pragma unroll
        for (int ni = 0; ni < 2; ++ni)
          acc[mi][ni] = MFMA(a[mi], b2[ni], acc[mi][ni]);
    }
    #pragma unroll
    for (int mi = 0; mi < 2; ++mi)
      #pragma unroll
      for (int ni = 0; ni < 2; ++ni) {
        int c = c0 + ni * 16 + rlo;
        float bias = bd[c];
        #pragma unroll
        for (int r = 0; r < 4; ++r) {
          int pix = pix0 + mi * 16 + slot * 4 + r;
          int byte = (pix * 256 + c * 2) ^ ((pix & 7) << 4);
          *(u16*)((char*)opL + byte) = f2bf(acc[mi][ni][r] + bias);
        }
      }
  }
  __syncthreads();

  #pragma unroll
  for (int q = 0; q < 2; ++q) {
    int u = q * 512 + t;
    int pix = u >> 4, off = u & 15;
    int byte = (pix * 256 + off * 16) ^ ((pix & 7) << 4);
    uint4 v = *(const uint4*)((const char*)opL + byte);
    int pixG = (l0 + (pix >> 5)) * 256 + m0 + (pix & 31);
    *(uint4*)(pN + (size_t)pixG * 128 + off * 8) = v;
  }
}

// ---------------------------------------------------------------------------
// K5: conv3x3 implicit-GEMM MFMA + XCD swizzle. FUSE_IN variant also reduces
// conv1's IN partials into folded (sc,b2) in LDS. grid 512.
// ---------------------------------------------------------------------------
#define CLOADB(s, B) {                                                        \
    _Pragma("unroll")                                                         \
    for (int j = 0; j < 2; ++j) {                                             \
      const int st_ = (s) + j;                                                \
      _Pragma("unroll")                                                       \
      for (int ni = 0; ni < 4; ++ni) {                                        \
        int co_ = co0 + ni * 16 + rlo;                                        \
        B[j][ni] = *(const s8v*)(wP +                                         \
            ((size_t)(st_ * 128 + co_) * 4 + slot) * 8);                      \
      }                                                                       \
    } }
#define CSTEP2(s, B) {                                                        \
    _Pragma("unroll")                                                         \
    for (int j = 0; j < 2; ++j) {                                             \
      const int st_ = (s) + j, tap_ = st_ >> 2, kk_ = st_ & 3;                \
      const int dy_ = tap_ / 3, dx_ = tap_ % 3;                               \
      s8v a_[4];                                                              \
      _Pragma("unroll")                                                       \
      for (int mi = 0; mi < 4; ++mi) {                                        \
        int p_ = mi * 16 + rlo + dx_;                                         \
        int lb_ = (((wpy + dy_) * 66 + p_) * 256 + kk_ * 64 + slot * 16) ^    \
                  ((p_ & 7) << 4);                                            \
        a_[mi] = *(const s8v*)((const char*)Ast + lb_);                       \
      }                                                                       \
      __builtin_amdgcn_s_setprio(1);                                          \
      _Pragma("unroll")                                                       \
      for (int mi = 0; mi < 4; ++mi)                                          \
        _Pragma("unroll")                                                     \
        for (int ni = 0; ni < 4; ++ni)                                        \
          acc[mi][ni] = MFMA(a_[mi], B[j][ni], acc[mi][ni]);                  \
      __builtin_amdgcn_s_setprio(0);                                          \
    } }

template<bool FUSE_IN>
__global__ __launch_bounds__(256, 2) void k_conv(const u16* __restrict__ inN,
                                                 const float* __restrict__ gSin,
                                                 const float* __restrict__ gQin,
                                                 const float* __restrict__ ing,
                                                 const float* __restrict__ inb,
                                                 const u16* __restrict__ wP,
                                                 u16* __restrict__ outB,
                                                 float* __restrict__ gSout,
                                                 float* __restrict__ gQout)
{
  __shared__ alignas(16) u16 Ast[4 * 66 * 128];   // 67584 B (reused as f32 out)
  __shared__ float partS[4][64], partQ[4][64];
  __shared__ alignas(16) float sstat[256];
  __shared__ float red2[4][128];
  int t = threadIdx.x, lane = t & 63, w = t >> 6;
  int rlo = lane & 15, slot = lane >> 4;
  int b = blockIdx.x;
  int L = (b & 7) * 64 + (b >> 3);               // XCD swizzle (512 % 8 == 0)
  int xt = L & 3, yt = L >> 2;
  int x0 = xt * 64, y0 = yt * 2;

  if constexpr (FUSE_IN) {
    int c = t & 127, h = t >> 7;
    float s = 0.f, q = 0.f;
    for (int i = h * 256; i < h * 256 + 256; ++i) {
      s += gSin[i * 128 + c];
      q += gQin[i * 128 + c];
    }
    red2[h][c] = s; red2[2 + h][c] = q;
    __syncthreads();
    if (t < 128) {
      float ss = red2[0][t] + red2[1][t];
      float qq = red2[2][t] + red2[3][t];
      float m = ss * (1.f / HW);
      float var = qq * (1.f / HW) - m * m;
      float rstd = rsqrtf(var + 1e-6f);
      float sc = rstd * ing[t];
      sstat[t] = sc;
      sstat[128 + t] = inb[t] - m * sc;
    }
    __syncthreads();
  }

  for (int u = t; u < 4224; u += 256) {
    int r = u / 1056;
    int rem = u - r * 1056;
    int p = rem >> 4, ku = rem & 15;
    int gy = y0 + r - 1, gx = x0 - 1 + p;
    s8v v = zero8();
    if ((unsigned)gy < 256u && (unsigned)gx < 256u) {
      v = *(const s8v*)(inN + ((size_t)gy * LL + gx) * 128 + ku * 8);
      if constexpr (FUSE_IN) {
        float4 s0 = ((const float4*)sstat)[ku * 2];
        float4 s1 = ((const float4*)sstat)[ku * 2 + 1];
        float4 q0 = ((const float4*)(sstat + 128))[ku * 2];
        float4 q1 = ((const float4*)(sstat + 128))[ku * 2 + 1];
        float f0 = elu1(bf2f((u16)v[0]) * s0.x + q0.x);
        float f1 = elu1(bf2f((u16)v[1]) * s0.y + q0.y);
        float f2 = elu1(bf2f((u16)v[2]) * s0.z + q0.z);
        float f3 = elu1(bf2f((u16)v[3]) * s0.w + q0.w);
        float f4 = elu1(bf2f((u16)v[4]) * s1.x + q1.x);
        float f5 = elu1(bf2f((u16)v[5]) * s1.y + q1.y);
        float f6 = elu1(bf2f((u16)v[6]) * s1.z + q1.z);
        float f7 = elu1(bf2f((u16)v[7]) * s1.w + q1.w);
        uint4 uv;
        uv.x = cvtpk2(f0, f1); uv.y = cvtpk2(f2, f3);
        uv.z = cvtpk2(f4, f5); uv.w = cvtpk2(f6, f7);
        v = __builtin_bit_cast(s8v, uv);
      }
    }
    int lb = (u * 16) ^ ((p & 7) << 4);
    *(s8v*)((char*)Ast + lb) = v;
  }
  __syncthreads();
  int wpy = w >> 1, co0 = (w & 1) * 64;
  f4v acc[4][4] = {};
  s8v bA[2][4], bB[2][4];
  CLOADB(0, bA)
  #pragma unroll
  for (int s = 0; s < 36; s += 4) {
    CLOADB(s + 2, bB)
    CSTEP2(s, bA)
    if (s + 4 < 36) { CLOADB(s + 4, bA) }
    CSTEP2(s + 2, bB)
  }
  // IN partial stats from registers
  #pragma unroll
  for (int ni = 0; ni < 4; ++ni) {
    float s = 0.f, q = 0.f;
    #pragma unroll
    for (int mi = 0; mi < 4; ++mi)
      #pragma unroll
      for (int r = 0; r < 4; ++r) {
        float v = acc[mi][ni][r];
        s += v; q += v * v;
      }
    s += __shfl_xor(s, 16); s += __shfl_xor(s, 32);
    q += __shfl_xor(q, 16); q += __shfl_xor(q, 32);
    if (slot == 0) { partS[w][ni * 16 + rlo] = s; partQ[w][ni * 16 + rlo] = q; }
  }
  __syncthreads();           // all Ast reads done; safe to reuse
  float* AstF = (float*)Ast; // [wpy][64 px][128 co] f32, XOR (pix&7)<<4
  #pragma unroll
  for (int mi = 0; mi < 4; ++mi)
    #pragma unroll
    for (int ni = 0; ni < 4; ++ni) {
      int co = co0 + ni * 16 + rlo;
      #pragma unroll
      for (int r = 0; r < 4; ++r) {
        int pix = mi * 16 + slot * 4 + r;
        int byte = wpy * 32768 + ((pix * 512 + co * 4) ^ ((pix & 7) << 4));
        *(float*)((char*)AstF + byte) = acc[mi][ni][r];
      }
    }
  if (t < 128) {
    int half = t >> 6, cl = t & 63;
    gSout[b * 128 + t] = partS[half][cl] + partS[2 + half][cl];
    gQout[b * 128 + t] = partQ[half][cl] + partQ[2 + half][cl];
  }
  __syncthreads();
  #pragma unroll
  for (int it = 0; it < 8; ++it) {
    int u = it * 256 + t;                   // 2048 units of 8 channels
    int wpy2 = u >> 10, rem = u & 1023;
    int pix = rem >> 4, cv8 = rem & 15;
    int base = wpy2 * 32768;
    int b0b = base + ((pix * 512 + cv8 * 32) ^ ((pix & 7) << 4));
    int b1b = base + ((pix * 512 + cv8 * 32 + 16) ^ ((pix & 7) << 4));
    float4 a = *(const float4*)((const char*)AstF + b0b);
    float4 bv = *(const float4*)((const char*)AstF + b1b);
    uint4 o;
    o.x = cvtpk2(a.x, a.y); o.y = cvtpk2(a.z, a.w);
    o.z = cvtpk2(bv.x, bv.y); o.w = cvtpk2(bv.z, bv.w);
    *(uint4*)(outB + ((size_t)(y0 + wpy2) * LL + x0 + pix) * 128 + cv8 * 8) = o;
  }
}

// ---------------------------------------------------------------------------
// K6: PARALLEL stats reduce: one block per channel (grid 128, block 512).
// ---------------------------------------------------------------------------
__global__ __launch_bounds__(512) void k_instat2(const float* __restrict__ gS,
                                                 const float* __restrict__ gQ,
                                                 const float* __restrict__ g,
                                                 const float* __restrict__ b,
                                                 float* __restrict__ st)
{
  __shared__ float redS[8], redQ[8];
  int c = blockIdx.x, t = threadIdx.x;
  int lane = t & 63, w = t >> 6;
  float s = gS[(size_t)t * 128 + c];
  float q = gQ[(size_t)t * 128 + c];
  #pragma unroll
  for (int off = 32; off; off >>= 1) {
    s += __shfl_down(s, off);
    q += __shfl_down(q, off);
  }
  if (lane == 0) { redS[w] = s; redQ[w] = q; }
  __syncthreads();
  if (t == 0) {
    float ss = 0.f, qq = 0.f;
    #pragma unroll
    for (int i = 0; i < 8; ++i) { ss += redS[i]; qq += redQ[i]; }
    float m = ss * (1.f / HW);
    float var = qq * (1.f / HW) - m * m;
    float rstd = rsqrtf(var + 1e-6f);
    float sc = rstd * g[c];
    st[c] = sc;
    st[128 + c] = b[c] - m * sc;
  }
}

// ---------------------------------------------------------------------------
// K7: out = elu(pN + IN2(h2raw)); 8-ch units. grid 4096.
// ---------------------------------------------------------------------------
__global__ __launch_bounds__(256) void k_final(const u16* __restrict__ pN,
                                               const u16* __restrict__ h2,
                                               const float* __restrict__ st,
                                               float* __restrict__ out)
{
  int i = blockIdx.x * 256 + threadIdx.x;   // 1,048,576 uint4 units
  int c8 = i & 15;
  uint4 hv = ((const uint4*)h2)[i];
  uint4 pv = ((const uint4*)pN)[i];
  float4 s0 = ((const float4*)st)[c8 * 2], s1 = ((const float4*)st)[c8 * 2 + 1];
  float4 q0 = ((const float4*)(st + 128))[c8 * 2], q1 = ((const float4*)(st + 128))[c8 * 2 + 1];
  float4 f0, f1;
  f0.x = bf2f((u16)(hv.x & 0xffff)) * s0.x + q0.x + bf2f((u16)(pv.x & 0xffff));
  f0.y = bf2f((u16)(hv.x >> 16))    * s0.y + q0.y + bf2f((u16)(pv.x >> 16));
  f0.z = bf2f((u16)(hv.y & 0xffff)) * s0.z + q0.z + bf2f((u16)(pv.y & 0xffff));
  f0.w = bf2f((u16)(hv.y >> 16))    * s0.w + q0.w + bf2f((u16)(pv.y >> 16));
  f1.x = bf2f((u16)(hv.z & 0xffff)) * s1.x + q1.x + bf2f((u16)(pv.z & 0xffff));
  f1.y = bf2f((u16)(hv.z >> 16))    * s1.y + q1.y + bf2f((u16)(pv.z >> 16));
  f1.z = bf2f((u16)(hv.w & 0xffff)) * s1.z + q1.z + bf2f((u16)(pv.w & 0xffff));
  f1.w = bf2f((u16)(hv.w >> 16))    * s1.w + q1.w + bf2f((u16)(pv.w >> 16));
  f0.x = elu1(f0.x); f0.y = elu1(f0.y); f0.z = elu1(f0.z); f0.w = elu1(f0.w);
  f1.x = elu1(f1.x); f1.y = elu1(f1.y); f1.z = elu1(f1.z); f1.w = elu1(f1.w);
  ((float4*)out)[(size_t)i * 2]     = f0;
  ((float4*)out)[(size_t)i * 2 + 1] = f1;
}

// ---------------------------------------------------------------------------
extern "C" void kernel_launch(void* const* d_in, const int* in_sizes, int n_in,
                              void* d_out, int out_size, void* d_ws, size_t ws_size,
                              hipStream_t stream)
{
  const float* msa   = (const float*)d_in[0];
  const float* pair  = (const float*)d_in[1];
  const float* ln_g  = (const float*)d_in[2];
  const float* ln_b  = (const float*)d_in[3];
  const float* Wl    = (const float*)d_in[4];
  const float* bl    = (const float*)d_in[5];
  const float* Wr    = (const float*)d_in[6];
  const float* br    = (const float*)d_in[7];
  const float* Wo    = (const float*)d_in[8];
  const float* bo    = (const float*)d_in[9];
  const float* Wd    = (const float*)d_in[10];
  const float* bd    = (const float*)d_in[11];
  const float* conv1 = (const float*)d_in[12];
  const float* in1_g = (const float*)d_in[13];
  const float* in1_b = (const float*)d_in[14];
  const float* conv2 = (const float*)d_in[15];
  const float* in2_g = (const float*)d_in[16];
  const float* in2_b = (const float*)d_in[17];
  float* out = (float*)d_out;

  // Workspace (F = 1Mi floats = 4 MB), peak ~86 MB.
  float* ws = (float*)d_ws;
  const size_t F = 1048576;
  u16* msaF   = (u16*)ws;
  u16* leftT  = (u16*)(ws + 4 * F);
  u16* rightT = (u16*)(ws + 4 * F + F / 2);
  u16* leftF  = (u16*)(ws + 5 * F);
  u16* rightF = (u16*)(ws + 5 * F + F / 2);
  u16* pN     = (u16*)(ws + 6 * F);
  u16* h1raw  = (u16*)(ws + 10 * F);
  u16* h2raw  = (u16*)(ws + 14 * F);
  u16* pairF  = (u16*)(ws + 18 * F);
  float* gS1  = ws + 22 * F;                 // 65536
  float* gQ1  = ws + 22 * F + 65536;
  float* gS2  = ws + 22 * F + 131072;
  float* gQ2  = ws + 22 * F + 196608;
  float* stats = ws + 22 * F + 262144;       // 256
  u16* aux    = (u16*)(ws + 22 * F + 262400);
  u16* wP1    = aux;                         // 147456
  u16* wP2    = aux + 147456;                // 147456
  u16* WoF    = aux + 294912;                // 131072
  u16* WdF    = aux + 425984;                // 32768
  u16* WlrF   = aux + 458752;                // 16384

  k_prep_ln<<<dim3(6376), dim3(256), 0, stream>>>(Wl, Wr, Wo, Wd, conv1, conv2,
                                                  pair, msa, ln_g, ln_b,
                                                  WlrF, WoF, WdF, wP1, wP2, pairF, msaF);
  k_gemm_lr<<<dim3(256), dim3(256), 0, stream>>>(msaF, WlrF, bl, br, leftT, rightT);
  k_fragpack<<<dim3(256), dim3(256), 0, stream>>>(leftT, rightT, leftF, rightF);

  k_fused<<<dim3(1024), dim3(512), 0, stream>>>(leftF, rightF, WoF, pairF, WdF,
                                                bo, bd, pN);

  k_conv<false><<<dim3(512), dim3(256), 0, stream>>>(pN, nullptr, nullptr,
                                                     nullptr, nullptr,
                                                     wP1, h1raw, gS1, gQ1);
  k_conv<true><<<dim3(512), dim3(256), 0, stream>>>(h1raw, gS1, gQ1, in1_g, in1_b,
                                                    wP2, h2raw, gS2, gQ2);
  k_instat2<<<dim3(128), dim3(512), 0, stream>>>(gS2, gQ2, in2_g, in2_b, stats);

  k_final<<<dim3(4096), dim3(256), 0, stream>>>(pN, h2raw, stats, out);
}